// Round 7
// baseline (248.652 us; speedup 1.0000x reference)
//
#include <hip/hip_runtime.h>
#include <math.h>

#define B_   2
#define LQ_  10723
#define D_   256
#define NH_  8
#define HD_  32
#define NL_  4
#define NP_  4
#define DFF_ 1024
#define M_   (B_ * LQ_)   // 21446

typedef __attribute__((ext_vector_type(4))) float f32x4;
typedef __attribute__((ext_vector_type(8))) short short8;
typedef __attribute__((ext_vector_type(4))) unsigned short us4;
typedef __attribute__((ext_vector_type(4))) unsigned int u32x4;
typedef u32x4 u32x4_a8 __attribute__((aligned(8)));   // 8B-aligned 16B load

__device__ __forceinline__ unsigned short f2bf(float f) {
    union { float f; unsigned int u; } x; x.f = f;
    unsigned int r = x.u + 0x7FFF + ((x.u >> 16) & 1);   // RNE
    return (unsigned short)(r >> 16);
}
__device__ __forceinline__ float bflo(unsigned int u) {
    union { unsigned int u; float f; } x; x.u = u << 16; return x.f;
}
__device__ __forceinline__ float bfhi(unsigned int u) {
    union { unsigned int u; float f; } x; x.u = u & 0xffff0000u; return x.f;
}

#define AS3U(p) ((__attribute__((address_space(3))) unsigned int*)(uintptr_t)(p))
#define AS1U(p) ((const __attribute__((address_space(1))) unsigned int*)(uintptr_t)(p))

// ---------------------------------------------------------------------------
// Fused prep: weight transpose/convert + bias concat + activation convert.
// idx < 754048: weights/bias; then value->bf16 (n4 float4 groups); then q=bf16(query+qpos).
// ---------------------------------------------------------------------------
__global__ __launch_bounds__(256) void prep_kernel(
    const float* __restrict__ Wv, const float* __restrict__ Woff,
    const float* __restrict__ Wattn, const float* __restrict__ Wout,
    const float* __restrict__ W1, const float* __restrict__ W2,
    const float* __restrict__ b_off, const float* __restrict__ b_attn,
    const float* __restrict__ value, const float* __restrict__ query,
    const float* __restrict__ qpos,
    unsigned short* __restrict__ WvT, unsigned short* __restrict__ WoaT,
    unsigned short* __restrict__ WoutT, unsigned short* __restrict__ W1T,
    unsigned short* __restrict__ W2T, float* __restrict__ b_oa,
    unsigned short* __restrict__ v16, unsigned short* __restrict__ q16, int n4)
{
    int idx = blockIdx.x * 256 + threadIdx.x;
    if (idx < 65536) {
        int n = idx >> 8, k = idx & 255;
        WvT[idx] = f2bf(Wv[k * 256 + n]);
    } else if (idx < 163840) {
        int l = idx - 65536; int n = l >> 8, k = l & 255;
        WoaT[l] = f2bf(n < 256 ? Woff[k * 256 + n] : Wattn[k * 128 + (n - 256)]);
    } else if (idx < 229376) {
        int l = idx - 163840; int n = l >> 8, k = l & 255;
        WoutT[l] = f2bf(Wout[k * 256 + n]);
    } else if (idx < 491520) {
        int l = idx - 229376; int n = l >> 8, k = l & 255;
        W1T[l] = f2bf(W1[k * 1024 + n]);
    } else if (idx < 753664) {
        int l = idx - 491520; int n = l >> 10, k = l & 1023;
        W2T[l] = f2bf(W2[k * 256 + n]);
    } else if (idx < 754048) {
        int l = idx - 753664;
        b_oa[l] = (l < 256) ? b_off[l] : b_attn[l - 256];
    } else if (idx < 754048 + n4) {
        int i = idx - 754048;
        float4 v = reinterpret_cast<const float4*>(value)[i];
        us4 r = { f2bf(v.x), f2bf(v.y), f2bf(v.z), f2bf(v.w) };
        reinterpret_cast<us4*>(v16)[i] = r;
    } else if (idx < 754048 + 2 * n4) {
        int j = idx - 754048 - n4;
        float4 va = reinterpret_cast<const float4*>(query)[j];
        float4 vb = reinterpret_cast<const float4*>(qpos)[j];
        us4 r = { f2bf(va.x + vb.x), f2bf(va.y + vb.y), f2bf(va.z + vb.z), f2bf(va.w + vb.w) };
        reinterpret_cast<us4*>(q16)[j] = r;
    }
}

// ---------------------------------------------------------------------------
// Fused vproj + off/attn GEMM dispatch. 128x128 tile, BK=32, K=256, 2-phase.
// blockIdx.x < 2 : vproj = v16 @ WvT^T + b_v -> bf16 [b][h][cq][lv][4ch]
// blockIdx.x >= 2: oa    = q16 @ WoaT^T + b_oa -> f32 (M,384)
// ---------------------------------------------------------------------------
__global__ __launch_bounds__(256) void gemm_pre(
    const unsigned short* __restrict__ v16, const unsigned short* __restrict__ q16,
    const unsigned short* __restrict__ WvT, const unsigned short* __restrict__ WoaT,
    const float* __restrict__ b_v, const float* __restrict__ b_oa,
    unsigned short* __restrict__ vph, float* __restrict__ oa)
{
    __shared__ unsigned short As[2][128 * 32];
    __shared__ unsigned short Bs[2][128 * 32];

    const bool is_v = (blockIdx.x < 2);
    const unsigned short* A  = is_v ? v16 : q16;
    const unsigned short* BT = is_v ? WvT : WoaT;
    const float* bias = is_v ? b_v : b_oa;
    const int n0 = (is_v ? (int)blockIdx.x : (int)blockIdx.x - 2) * 128;
    const int K = 256;

    const int tid  = threadIdx.x;
    const int wave = tid >> 6;
    const int lane = tid & 63;
    const int m0 = blockIdx.y * 128;
    const int wr = (wave >> 1) * 64;
    const int wc = (wave & 1) * 64;

    f32x4 acc[4][4] = {};
    const int soff = wave * 1024 + lane * 16;

    auto stage = [&](int buf, int k0) {
        #pragma unroll
        for (int p = 0; p < 2; ++p) {
            const int off  = p * 4096 + soff;
            const int row  = off >> 6;
            const int colb = off & 63;
            int ar = m0 + row; ar = (ar < M_) ? ar : (M_ - 1);
            __builtin_amdgcn_global_load_lds(AS1U(A + (size_t)ar * K + k0 + (colb >> 1)),
                AS3U(&As[buf][(p * 4096 + wave * 1024) >> 1]), 16, 0, 0);
            __builtin_amdgcn_global_load_lds(AS1U(BT + (size_t)(n0 + row) * K + k0 + (colb >> 1)),
                AS3U(&Bs[buf][(p * 4096 + wave * 1024) >> 1]), 16, 0, 0);
        }
    };

    stage(0, 0);
    __syncthreads();
    int cur = 0;
    for (int t = 0; t < 8; ++t) {
        if (t + 1 < 8) stage(cur ^ 1, (t + 1) * 32);
        const int fr = lane & 15;
        const int kb = (lane >> 4) * 8;
        short8 af[4], bf[4];
        #pragma unroll
        for (int m = 0; m < 4; ++m)
            af[m] = *reinterpret_cast<const short8*>(&As[cur][(wr + m * 16 + fr) * 32 + kb]);
        #pragma unroll
        for (int n = 0; n < 4; ++n)
            bf[n] = *reinterpret_cast<const short8*>(&Bs[cur][(wc + n * 16 + fr) * 32 + kb]);
        #pragma unroll
        for (int m = 0; m < 4; ++m)
            #pragma unroll
            for (int n = 0; n < 4; ++n)
                acc[m][n] = __builtin_amdgcn_mfma_f32_16x16x32_bf16(af[m], bf[n], acc[m][n], 0, 0, 0);
        if (t + 1 < 8) { __syncthreads(); cur ^= 1; }
    }

    const int fr = lane & 15;
    const int r0 = (lane >> 4) * 4;
    #pragma unroll
    for (int n = 0; n < 4; ++n) {
        const int col = n0 + wc + n * 16 + fr;
        const float bv = bias[col];
        #pragma unroll
        for (int m = 0; m < 4; ++m) {
            #pragma unroll
            for (int r = 0; r < 4; ++r) {
                const int row = m0 + wr + m * 16 + r0 + r;
                if (row < M_) {
                    float v = acc[m][n][r] + bv;
                    if (is_v) {
                        // [b][h][cq][lv][4ch]
                        const int bb = (row >= LQ_) ? 1 : 0;
                        const int lv = row - bb * LQ_;
                        const int hh = col >> 5, cq = (col >> 2) & 7, ch = col & 3;
                        vph[((((size_t)bb * NH_ + hh) * 8 + cq) * LQ_ + lv) * 4 + ch] = f2bf(v);
                    } else {
                        oa[(size_t)row * 384 + col] = v;
                    }
                }
            }
        }
    }
}

// ---------------------------------------------------------------------------
// Generic MFMA bf16 GEMM (FFN1 use): 128x128 tile, BK=32, 2-phase dbuf.
// ---------------------------------------------------------------------------
template<int RELU, int OUT_BF16>
__global__ __launch_bounds__(256) void gemm_mfma(
    const unsigned short* __restrict__ A,
    const unsigned short* __restrict__ BT,
    const float* __restrict__ bias,
    void* __restrict__ Cout,
    int M, int N, int K)
{
    __shared__ unsigned short As[2][128 * 32];
    __shared__ unsigned short Bs[2][128 * 32];

    const int tid  = threadIdx.x;
    const int wave = tid >> 6;
    const int lane = tid & 63;
    const int m0 = blockIdx.y * 128;
    const int n0 = blockIdx.x * 128;
    const int wr = (wave >> 1) * 64;
    const int wc = (wave & 1) * 64;

    f32x4 acc[4][4] = {};
    const int soff = wave * 1024 + lane * 16;

    auto stage = [&](int buf, int k0) {
        #pragma unroll
        for (int p = 0; p < 2; ++p) {
            const int off  = p * 4096 + soff;
            const int row  = off >> 6;
            const int colb = off & 63;
            int ar = m0 + row; ar = (ar < M) ? ar : (M - 1);
            __builtin_amdgcn_global_load_lds(AS1U(A + (size_t)ar * K + k0 + (colb >> 1)),
                AS3U(&As[buf][(p * 4096 + wave * 1024) >> 1]), 16, 0, 0);
            __builtin_amdgcn_global_load_lds(AS1U(BT + (size_t)(n0 + row) * K + k0 + (colb >> 1)),
                AS3U(&Bs[buf][(p * 4096 + wave * 1024) >> 1]), 16, 0, 0);
        }
    };

    const int nt = K >> 5;
    stage(0, 0);
    __syncthreads();
    int cur = 0;
    for (int t = 0; t < nt; ++t) {
        if (t + 1 < nt) stage(cur ^ 1, (t + 1) * 32);
        const int fr = lane & 15;
        const int kb = (lane >> 4) * 8;
        short8 af[4], bf[4];
        #pragma unroll
        for (int m = 0; m < 4; ++m)
            af[m] = *reinterpret_cast<const short8*>(&As[cur][(wr + m * 16 + fr) * 32 + kb]);
        #pragma unroll
        for (int n = 0; n < 4; ++n)
            bf[n] = *reinterpret_cast<const short8*>(&Bs[cur][(wc + n * 16 + fr) * 32 + kb]);
        #pragma unroll
        for (int m = 0; m < 4; ++m)
            #pragma unroll
            for (int n = 0; n < 4; ++n)
                acc[m][n] = __builtin_amdgcn_mfma_f32_16x16x32_bf16(af[m], bf[n], acc[m][n], 0, 0, 0);
        if (t + 1 < nt) { __syncthreads(); cur ^= 1; }
    }

    const int fr = lane & 15;
    const int r0 = (lane >> 4) * 4;
    #pragma unroll
    for (int n = 0; n < 4; ++n) {
        const int col = n0 + wc + n * 16 + fr;
        const float bv = bias[col];
        #pragma unroll
        for (int m = 0; m < 4; ++m) {
            #pragma unroll
            for (int r = 0; r < 4; ++r) {
                const int row = m0 + wr + m * 16 + r0 + r;
                if (row < M) {
                    float v = acc[m][n][r] + bv;
                    if (RELU) v = fmaxf(v, 0.f);
                    if (OUT_BF16)
                        ((unsigned short*)Cout)[(size_t)row * N + col] = f2bf(v);
                    else
                        ((float*)Cout)[(size_t)row * N + col] = v;
                }
            }
        }
    }
}

// ---------------------------------------------------------------------------
// GEMM (N=256) + bias + residual + LayerNorm, fused. 2-phase double-buffered.
// BM=64, BN=256, BK=32, 512 threads = 8 waves (2 row x 4 col).
// ---------------------------------------------------------------------------
template<int MIRROR>
__global__ __launch_bounds__(512) void gemm_ln(
    const unsigned short* __restrict__ A,
    const unsigned short* __restrict__ BT,
    const float* __restrict__ bias,
    const float* __restrict__ res,
    const float* __restrict__ g,
    const float* __restrict__ beta,
    float* __restrict__ outf,
    unsigned short* __restrict__ out16,
    int M, int K)
{
    __shared__ unsigned short As[2][64 * 32];
    __shared__ unsigned short Bs[2][256 * 32];
    __shared__ float2 sRed[4][64];

    const int tid  = threadIdx.x;
    const int wave = tid >> 6;
    const int lane = tid & 63;
    const int m0 = blockIdx.x * 64;
    const int wr = (wave >> 2) * 32;
    const int wc = (wave & 3) * 64;

    f32x4 acc[2][4] = {};

    auto stage = [&](int buf, int k0) {
        if (tid < 256) {
            const int off  = tid * 16;
            const int row  = off >> 6;
            const int colb = off & 63;
            int ar = m0 + row; ar = (ar < M) ? ar : (M - 1);
            __builtin_amdgcn_global_load_lds(AS1U(A + (size_t)ar * K + k0 + (colb >> 1)),
                AS3U(&As[buf][(wave * 1024) >> 1]), 16, 0, 0);
        }
        #pragma unroll
        for (int p = 0; p < 2; ++p) {
            const int off  = p * 8192 + tid * 16;
            const int row  = off >> 6;
            const int colb = off & 63;
            __builtin_amdgcn_global_load_lds(AS1U(BT + (size_t)row * K + k0 + (colb >> 1)),
                AS3U(&Bs[buf][(p * 8192 + wave * 1024) >> 1]), 16, 0, 0);
        }
    };

    const int nt = K >> 5;
    stage(0, 0);
    __syncthreads();
    int cur = 0;
    for (int t = 0; t < nt; ++t) {
        if (t + 1 < nt) stage(cur ^ 1, (t + 1) * 32);
        const int fr = lane & 15;
        const int kb = (lane >> 4) * 8;
        short8 af[2], bf[4];
        #pragma unroll
        for (int m = 0; m < 2; ++m)
            af[m] = *reinterpret_cast<const short8*>(&As[cur][(wr + m * 16 + fr) * 32 + kb]);
        #pragma unroll
        for (int n = 0; n < 4; ++n)
            bf[n] = *reinterpret_cast<const short8*>(&Bs[cur][(wc + n * 16 + fr) * 32 + kb]);
        #pragma unroll
        for (int m = 0; m < 2; ++m)
            #pragma unroll
            for (int n = 0; n < 4; ++n)
                acc[m][n] = __builtin_amdgcn_mfma_f32_16x16x32_bf16(af[m], bf[n], acc[m][n], 0, 0, 0);
        if (t + 1 < nt) { __syncthreads(); cur ^= 1; }
    }

    const int fr = lane & 15;
    const int r0 = (lane >> 4) * 4;
    float biasv[4], gv[4], bev[4];
    #pragma unroll
    for (int n = 0; n < 4; ++n) {
        const int col = wc + n * 16 + fr;
        biasv[n] = bias[col]; gv[n] = g[col]; bev[n] = beta[col];
    }
    #pragma unroll
    for (int m = 0; m < 2; ++m) {
        #pragma unroll
        for (int r = 0; r < 4; ++r) {
            int row = m0 + wr + m * 16 + r0 + r;
            int rr = (row < M) ? row : (M - 1);
            const float* rp = res + (size_t)rr * 256;
            #pragma unroll
            for (int n = 0; n < 4; ++n)
                acc[m][n][r] += biasv[n] + rp[wc + n * 16 + fr];
        }
    }
    #pragma unroll
    for (int m = 0; m < 2; ++m) {
        #pragma unroll
        for (int r = 0; r < 4; ++r) {
            float sx = 0.f, sxx = 0.f;
            #pragma unroll
            for (int n = 0; n < 4; ++n) { float t = acc[m][n][r]; sx += t; sxx += t * t; }
            #pragma unroll
            for (int mask = 1; mask < 16; mask <<= 1) {
                sx  += __shfl_xor(sx, mask);
                sxx += __shfl_xor(sxx, mask);
            }
            if (fr == 0) sRed[wave & 3][wr + m * 16 + r0 + r] = make_float2(sx, sxx);
        }
    }
    __syncthreads();
    #pragma unroll
    for (int m = 0; m < 2; ++m) {
        #pragma unroll
        for (int r = 0; r < 4; ++r) {
            const int lr = wr + m * 16 + r0 + r;
            float2 a0 = sRed[0][lr], a1 = sRed[1][lr], a2 = sRed[2][lr], a3 = sRed[3][lr];
            const float S  = a0.x + a1.x + a2.x + a3.x;
            const float SS = a0.y + a1.y + a2.y + a3.y;
            const float mean = S * (1.f / 256.f);
            const float var  = SS * (1.f / 256.f) - mean * mean;
            const float rstd = rsqrtf(var + 1e-5f);
            const int row = m0 + lr;
            if (row < M) {
                #pragma unroll
                for (int n = 0; n < 4; ++n) {
                    const int col = wc + n * 16 + fr;
                    const float y = (acc[m][n][r] - mean) * rstd * gv[n] + bev[n];
                    outf[(size_t)row * 256 + col] = y;
                    if (MIRROR) out16[(size_t)row * 256 + col] = f2bf(y);
                }
            }
        }
    }
}

// ---------------------------------------------------------------------------
// Multi-scale deformable attention, XCD-local by head, paired-corner 16B gathers.
// vproj_h: bf16 [b][h][cq(8)][lv][4ch].  Block = (qc, bh); 4 waves x 8 queries.
// Phase 1: per point, 2 row-base byte offsets + 4 half-weights.
// Phase 2: per point, 2 x 16B loads (covers both x-corners), dual accumulators.
// ---------------------------------------------------------------------------
__global__ __launch_bounds__(256) void msdeform_kernel(
    const unsigned short* __restrict__ vproj_h, const float* __restrict__ offattn,
    const float* __restrict__ refp, unsigned short* __restrict__ msout)
{
    __shared__ int2   sOff[4][8][17];
    __shared__ float4 sW[4][8][17];

    const int bh = blockIdx.x & 15;          // b*8 + h
    const int qc = blockIdx.x >> 4;
    const int b  = bh >> 3;
    const int h  = bh & 7;
    const int wave = threadIdx.x >> 6;
    const int lane = threadIdx.x & 63;
    const int qw = lane >> 3;                // query within wave
    const int k  = lane & 7;                 // phase1: point-pair; phase2: channel-quad
    const int lv = qc * 32 + wave * 8 + qw;
    if (lv >= LQ_) return;
    const int bq = b * LQ_ + lv;

    // ---- phase 1 ----
    const float4 o4  = *reinterpret_cast<const float4*>(offattn + (size_t)bq * 384 + h * 32 + 4 * k);
    const float2 lg2 = *reinterpret_cast<const float2*>(offattn + (size_t)bq * 384 + 256 + h * 16 + 2 * k);
    const int l = k >> 1;
    const float2 rp  = *reinterpret_cast<const float2*>(refp + (size_t)bq * 8 + 2 * l);

    const float Wf[4] = {106.f, 53.f, 27.f, 14.f};
    const float Hf[4] = {76.f, 38.f, 19.f, 10.f};
    const int   Wi[4] = {106, 53, 27, 14};
    const int   Hi[4] = {76, 38, 19, 10};
    const int   St[4] = {0, 8056, 10070, 10583};

    float mx = fmaxf(lg2.x, lg2.y);
    mx = fmaxf(mx, __shfl_xor(mx, 1));
    mx = fmaxf(mx, __shfl_xor(mx, 2));
    mx = fmaxf(mx, __shfl_xor(mx, 4));
    const float e0 = __expf(lg2.x - mx), e1 = __expf(lg2.y - mx);
    float s = e0 + e1;
    s += __shfl_xor(s, 1); s += __shfl_xor(s, 2); s += __shfl_xor(s, 4);
    const float inv = 1.f / s;

    const int W = Wi[l], H = Hi[l];
    const float Wff = Wf[l], Hff = Hf[l];
    const int base = St[l];

    #pragma unroll
    for (int pp = 0; pp < 2; ++pp) {
        const float ox = pp ? o4.z : o4.x;
        const float oy = pp ? o4.w : o4.y;
        const float aw = (pp ? e1 : e0) * inv;
        const float x = fmaf(rp.x, Wff, ox) - 0.5f;
        const float y = fmaf(rp.y, Hff, oy) - 0.5f;
        const float xf = floorf(x), yf = floorf(y);
        const float fx = x - xf, fy = y - yf;
        const int x0 = (int)xf, y0 = (int)yf;
        // x-half weights with validity
        const float wx0v = ((x0 >= 0) && (x0 < W)) ? (1.f - fx) : 0.f;
        const float wx1v = ((x0 + 1 >= 0) && (x0 + 1 < W)) ? fx : 0.f;
        const int bx = min(max(x0, 0), W - 2);
        const float h0 = (x0 == bx) ? wx0v : wx1v;
        const float h1 = (x0 == bx) ? wx1v : wx0v;
        // y rows with validity
        const float gy0 = (((y0 >= 0) && (y0 < H)) ? (1.f - fy) : 0.f) * aw;
        const float fy1 = (((y0 + 1 >= 0) && (y0 + 1 < H)) ? fy : 0.f) * aw;
        const int yc0 = min(max(y0, 0), H - 1);
        const int yc1 = min(max(y0 + 1, 0), H - 1);
        int2 ov;
        ov.x = (base + yc0 * W + bx) << 3;   // byte offset (8 B per lv)
        ov.y = (base + yc1 * W + bx) << 3;
        sOff[wave][qw][2 * k + pp] = ov;
        sW[wave][qw][2 * k + pp] = make_float4(h0 * gy0, h1 * gy0, h0 * fy1, h1 * fy1);
    }

    // ---- phase 2: gather (lane: query qw, channel-quad k) ----
    const char* vb = (const char*)(vproj_h + (((size_t)bh * 8 + k) * LQ_) * 4);
    f32x4 acc0 = {0.f, 0.f, 0.f, 0.f};
    f32x4 acc1 = {0.f, 0.f, 0.f, 0.f};
    #pragma unroll
    for (int p = 0; p < 16; ++p) {
        const int2   ov = sOff[wave][qw][p];
        const float4 w4 = sW[wave][qw][p];
        u32x4 r0 = *reinterpret_cast<const u32x4_a8*>(vb + ov.x);
        acc0[0] = fmaf(w4.x, bflo(r0.x), acc0[0]);
        acc0[1] = fmaf(w4.x, bfhi(r0.x), acc0[1]);
        acc0[2] = fmaf(w4.x, bflo(r0.y), acc0[2]);
        acc0[3] = fmaf(w4.x, bfhi(r0.y), acc0[3]);
        acc1[0] = fmaf(w4.y, bflo(r0.z), acc1[0]);
        acc1[1] = fmaf(w4.y, bfhi(r0.z), acc1[1]);
        acc1[2] = fmaf(w4.y, bflo(r0.w), acc1[2]);
        acc1[3] = fmaf(w4.y, bfhi(r0.w), acc1[3]);
        u32x4 r1 = *reinterpret_cast<const u32x4_a8*>(vb + ov.y);
        acc0[0] = fmaf(w4.z, bflo(r1.x), acc0[0]);
        acc0[1] = fmaf(w4.z, bfhi(r1.x), acc0[1]);
        acc0[2] = fmaf(w4.z, bflo(r1.y), acc0[2]);
        acc0[3] = fmaf(w4.z, bfhi(r1.y), acc0[3]);
        acc1[0] = fmaf(w4.w, bflo(r1.z), acc1[0]);
        acc1[1] = fmaf(w4.w, bfhi(r1.z), acc1[1]);
        acc1[2] = fmaf(w4.w, bflo(r1.w), acc1[2]);
        acc1[3] = fmaf(w4.w, bfhi(r1.w), acc1[3]);
    }
    us4 r = { f2bf(acc0[0] + acc1[0]), f2bf(acc0[1] + acc1[1]),
              f2bf(acc0[2] + acc1[2]), f2bf(acc0[3] + acc1[3]) };
    *reinterpret_cast<us4*>(msout + (size_t)bq * 256 + h * 32 + k * 4) = r;
}

// ---------------------------------------------------------------------------
extern "C" void kernel_launch(void* const* d_in, const int* in_sizes, int n_in,
                              void* d_out, int out_size, void* d_ws, size_t ws_size,
                              hipStream_t stream) {
    const float* query = (const float*)d_in[0];
    const float* qpos  = (const float*)d_in[1];
    const float* value = (const float*)d_in[2];
    const float* refp  = (const float*)d_in[3];
    const float* W_off  = (const float*)d_in[6];
    const float* b_off  = (const float*)d_in[7];
    const float* W_attn = (const float*)d_in[8];
    const float* b_attn = (const float*)d_in[9];
    const float* W_v    = (const float*)d_in[10];
    const float* b_v    = (const float*)d_in[11];
    const float* W_out  = (const float*)d_in[12];
    const float* b_out  = (const float*)d_in[13];
    const float* ln1_g  = (const float*)d_in[14];
    const float* ln1_b  = (const float*)d_in[15];
    const float* W1     = (const float*)d_in[16];
    const float* b1     = (const float*)d_in[17];
    const float* W2     = (const float*)d_in[18];
    const float* b2     = (const float*)d_in[19];
    const float* ln2_g  = (const float*)d_in[20];
    const float* ln2_b  = (const float*)d_in[21];
    float* out = (float*)d_out;

    // ---- workspace layout ----
    unsigned short* WvT   = (unsigned short*)d_ws;
    unsigned short* WoaT  = WvT   + 65536;    // 384 x 256  (off | attn)
    unsigned short* WoutT = WoaT  + 98304;
    unsigned short* W1T   = WoutT + 65536;    // 1024 x 256
    unsigned short* W2T   = W1T   + 262144;   // 256 x 1024
    float* b_oa = (float*)(W2T + 262144);     // 384 f32
    uint8_t* base = (uint8_t*)(b_oa + 384);
    base = (uint8_t*)(((uintptr_t)base + 255) & ~(uintptr_t)255);

    const size_t A = (size_t)M_ * D_;
    unsigned short* R_v16  = (unsigned short*)base;          // value bf16 -> q1 bf16 mirror
    unsigned short* R_q16  = R_v16 + A;                      // q bf16 -> ms16
    unsigned short* R_vph  = R_q16 + A;                      // vproj bf16 [b][h][cq][lv][4]
    float* R_oa  = (float*)(R_vph + A);                      // off|attn (M,384)
    float* R_q1  = R_oa + (size_t)M_ * 384;                  // q1 f32
    unsigned short* R_h16 = (unsigned short*)(R_q1 + A);     // FFN hidden bf16 (M,1024)

    const dim3 blk(256);
    auto cdiv = [](size_t a, size_t b) { return (unsigned)((a + b - 1) / b); };

    const int n4 = (int)(A / 4);
    prep_kernel<<<cdiv(754048 + 2 * (size_t)n4, 256), blk, 0, stream>>>(
        W_v, W_off, W_attn, W_out, W1, W2, b_off, b_attn, value, query, qpos,
        WvT, WoaT, WoutT, W1T, W2T, b_oa, R_v16, R_q16, n4);

    const unsigned MT = (M_ + 127) / 128;   // 168
    // vproj (head/cq-major bf16) + off|attn (f32), one dispatch
    gemm_pre<<<dim3(5, MT), blk, 0, stream>>>(
        R_v16, R_q16, WvT, WoaT, b_v, b_oa, R_vph, R_oa);
    // deformable attention -> ms16 (overwrites R_q16, dead)
    const unsigned nQC = cdiv(LQ_, 32);   // 336
    msdeform_kernel<<<dim3(nQC * 16), blk, 0, stream>>>(R_vph, R_oa, refp, R_q16);
    // q1 = LN(query + ms16@WoutT^T + b_out): f32 -> R_q1, bf16 -> R_v16 (dead)
    gemm_ln<1><<<dim3(cdiv(M_, 64)), dim3(512), 0, stream>>>(
        R_q16, WoutT, b_out, query, ln1_g, ln1_b, R_q1, R_v16, M_, 256);
    // h = relu(q1b @ W1T^T) bf16
    gemm_mfma<1, 1><<<dim3(8, MT), blk, 0, stream>>>(R_v16, W1T, b1, R_h16, M_, 1024, 256);
    // out = LN(q1 + h@W2T^T + b2)
    gemm_ln<0><<<dim3(cdiv(M_, 64)), dim3(512), 0, stream>>>(
        R_h16, W2T, b2, R_q1, ln2_g, ln2_b, out, nullptr, M_, 1024);
}

// Round 8
// 179.116 us; speedup vs baseline: 1.3882x; 1.3882x over previous
//
#include <hip/hip_runtime.h>
#include <math.h>

#define B_   2
#define LQ_  10723
#define D_   256
#define NH_  8
#define HD_  32
#define NL_  4
#define NP_  4
#define DFF_ 1024
#define M_   (B_ * LQ_)   // 21446

typedef __attribute__((ext_vector_type(4))) float f32x4;
typedef __attribute__((ext_vector_type(8))) short short8;
typedef __attribute__((ext_vector_type(4))) unsigned short us4;

__device__ __forceinline__ unsigned short f2bf(float f) {
    union { float f; unsigned int u; } x; x.f = f;
    unsigned int r = x.u + 0x7FFF + ((x.u >> 16) & 1);   // RNE
    return (unsigned short)(r >> 16);
}
__device__ __forceinline__ float bflo(unsigned int u) {
    union { unsigned int u; float f; } x; x.u = u << 16; return x.f;
}
__device__ __forceinline__ float bfhi(unsigned int u) {
    union { unsigned int u; float f; } x; x.u = u & 0xffff0000u; return x.f;
}

#define AS3U(p) ((__attribute__((address_space(3))) unsigned int*)(uintptr_t)(p))
#define AS1U(p) ((const __attribute__((address_space(1))) unsigned int*)(uintptr_t)(p))

// ---------------------------------------------------------------------------
// Fused prep: weight transpose/convert + bias concat + activation convert.
// ---------------------------------------------------------------------------
__global__ __launch_bounds__(256) void prep_kernel(
    const float* __restrict__ Wv, const float* __restrict__ Woff,
    const float* __restrict__ Wattn, const float* __restrict__ Wout,
    const float* __restrict__ W1, const float* __restrict__ W2,
    const float* __restrict__ b_off, const float* __restrict__ b_attn,
    const float* __restrict__ value, const float* __restrict__ query,
    const float* __restrict__ qpos,
    unsigned short* __restrict__ WvT, unsigned short* __restrict__ WoaT,
    unsigned short* __restrict__ WoutT, unsigned short* __restrict__ W1T,
    unsigned short* __restrict__ W2T, float* __restrict__ b_oa,
    unsigned short* __restrict__ v16, unsigned short* __restrict__ q16, int n4)
{
    int idx = blockIdx.x * 256 + threadIdx.x;
    if (idx < 65536) {
        int n = idx >> 8, k = idx & 255;
        WvT[idx] = f2bf(Wv[k * 256 + n]);
    } else if (idx < 163840) {
        int l = idx - 65536; int n = l >> 8, k = l & 255;
        WoaT[l] = f2bf(n < 256 ? Woff[k * 256 + n] : Wattn[k * 128 + (n - 256)]);
    } else if (idx < 229376) {
        int l = idx - 163840; int n = l >> 8, k = l & 255;
        WoutT[l] = f2bf(Wout[k * 256 + n]);
    } else if (idx < 491520) {
        int l = idx - 229376; int n = l >> 8, k = l & 255;
        W1T[l] = f2bf(W1[k * 1024 + n]);
    } else if (idx < 753664) {
        int l = idx - 491520; int n = l >> 10, k = l & 1023;
        W2T[l] = f2bf(W2[k * 256 + n]);
    } else if (idx < 754048) {
        int l = idx - 753664;
        b_oa[l] = (l < 256) ? b_off[l] : b_attn[l - 256];
    } else if (idx < 754048 + n4) {
        int i = idx - 754048;
        float4 v = reinterpret_cast<const float4*>(value)[i];
        us4 r = { f2bf(v.x), f2bf(v.y), f2bf(v.z), f2bf(v.w) };
        reinterpret_cast<us4*>(v16)[i] = r;
    } else if (idx < 754048 + 2 * n4) {
        int j = idx - 754048 - n4;
        float4 va = reinterpret_cast<const float4*>(query)[j];
        float4 vb = reinterpret_cast<const float4*>(qpos)[j];
        us4 r = { f2bf(va.x + vb.x), f2bf(va.y + vb.y), f2bf(va.z + vb.z), f2bf(va.w + vb.w) };
        reinterpret_cast<us4*>(q16)[j] = r;
    }
}

// ---------------------------------------------------------------------------
// Fused vproj + off/attn GEMM dispatch. 128x128 tile, BK=32, K=256, 2-phase.
// blockIdx.x < 2 : vproj = v16 @ WvT^T + b_v -> bf16 head-major [b][h][lv][32]
// blockIdx.x >= 2: oa    = q16 @ WoaT^T + b_oa -> f32 (M,384)
// ---------------------------------------------------------------------------
__global__ __launch_bounds__(256) void gemm_pre(
    const unsigned short* __restrict__ v16, const unsigned short* __restrict__ q16,
    const unsigned short* __restrict__ WvT, const unsigned short* __restrict__ WoaT,
    const float* __restrict__ b_v, const float* __restrict__ b_oa,
    unsigned short* __restrict__ vph, float* __restrict__ oa)
{
    __shared__ unsigned short As[2][128 * 32];
    __shared__ unsigned short Bs[2][128 * 32];

    const bool is_v = (blockIdx.x < 2);
    const unsigned short* A  = is_v ? v16 : q16;
    const unsigned short* BT = is_v ? WvT : WoaT;
    const float* bias = is_v ? b_v : b_oa;
    const int n0 = (is_v ? (int)blockIdx.x : (int)blockIdx.x - 2) * 128;
    const int K = 256;

    const int tid  = threadIdx.x;
    const int wave = tid >> 6;
    const int lane = tid & 63;
    const int m0 = blockIdx.y * 128;
    const int wr = (wave >> 1) * 64;
    const int wc = (wave & 1) * 64;

    f32x4 acc[4][4] = {};
    const int soff = wave * 1024 + lane * 16;

    auto stage = [&](int buf, int k0) {
        #pragma unroll
        for (int p = 0; p < 2; ++p) {
            const int off  = p * 4096 + soff;
            const int row  = off >> 6;
            const int colb = off & 63;
            int ar = m0 + row; ar = (ar < M_) ? ar : (M_ - 1);
            __builtin_amdgcn_global_load_lds(AS1U(A + (size_t)ar * K + k0 + (colb >> 1)),
                AS3U(&As[buf][(p * 4096 + wave * 1024) >> 1]), 16, 0, 0);
            __builtin_amdgcn_global_load_lds(AS1U(BT + (size_t)(n0 + row) * K + k0 + (colb >> 1)),
                AS3U(&Bs[buf][(p * 4096 + wave * 1024) >> 1]), 16, 0, 0);
        }
    };

    stage(0, 0);
    __syncthreads();
    int cur = 0;
    for (int t = 0; t < 8; ++t) {
        if (t + 1 < 8) stage(cur ^ 1, (t + 1) * 32);
        const int fr = lane & 15;
        const int kb = (lane >> 4) * 8;
        short8 af[4], bf[4];
        #pragma unroll
        for (int m = 0; m < 4; ++m)
            af[m] = *reinterpret_cast<const short8*>(&As[cur][(wr + m * 16 + fr) * 32 + kb]);
        #pragma unroll
        for (int n = 0; n < 4; ++n)
            bf[n] = *reinterpret_cast<const short8*>(&Bs[cur][(wc + n * 16 + fr) * 32 + kb]);
        #pragma unroll
        for (int m = 0; m < 4; ++m)
            #pragma unroll
            for (int n = 0; n < 4; ++n)
                acc[m][n] = __builtin_amdgcn_mfma_f32_16x16x32_bf16(af[m], bf[n], acc[m][n], 0, 0, 0);
        if (t + 1 < 8) { __syncthreads(); cur ^= 1; }
    }

    const int fr = lane & 15;
    const int r0 = (lane >> 4) * 4;
    #pragma unroll
    for (int n = 0; n < 4; ++n) {
        const int col = n0 + wc + n * 16 + fr;
        const float bv = bias[col];
        #pragma unroll
        for (int m = 0; m < 4; ++m) {
            #pragma unroll
            for (int r = 0; r < 4; ++r) {
                const int row = m0 + wr + m * 16 + r0 + r;
                if (row < M_) {
                    float v = acc[m][n][r] + bv;
                    if (is_v) {
                        // head-major: [b][h][lv][32]
                        const int bb = (row >= LQ_) ? 1 : 0;
                        const int lv = row - bb * LQ_;
                        const int hh = col >> 5, dd = col & 31;
                        vph[(((size_t)bb * NH_ + hh) * LQ_ + lv) * 32 + dd] = f2bf(v);
                    } else {
                        oa[(size_t)row * 384 + col] = v;
                    }
                }
            }
        }
    }
}

// ---------------------------------------------------------------------------
// Generic MFMA bf16 GEMM (FFN1 use): 128x128 tile, BK=32, 2-phase dbuf.
// ---------------------------------------------------------------------------
template<int RELU, int OUT_BF16>
__global__ __launch_bounds__(256) void gemm_mfma(
    const unsigned short* __restrict__ A,
    const unsigned short* __restrict__ BT,
    const float* __restrict__ bias,
    void* __restrict__ Cout,
    int M, int N, int K)
{
    __shared__ unsigned short As[2][128 * 32];
    __shared__ unsigned short Bs[2][128 * 32];

    const int tid  = threadIdx.x;
    const int wave = tid >> 6;
    const int lane = tid & 63;
    const int m0 = blockIdx.y * 128;
    const int n0 = blockIdx.x * 128;
    const int wr = (wave >> 1) * 64;
    const int wc = (wave & 1) * 64;

    f32x4 acc[4][4] = {};
    const int soff = wave * 1024 + lane * 16;

    auto stage = [&](int buf, int k0) {
        #pragma unroll
        for (int p = 0; p < 2; ++p) {
            const int off  = p * 4096 + soff;
            const int row  = off >> 6;
            const int colb = off & 63;
            int ar = m0 + row; ar = (ar < M) ? ar : (M - 1);
            __builtin_amdgcn_global_load_lds(AS1U(A + (size_t)ar * K + k0 + (colb >> 1)),
                AS3U(&As[buf][(p * 4096 + wave * 1024) >> 1]), 16, 0, 0);
            __builtin_amdgcn_global_load_lds(AS1U(BT + (size_t)(n0 + row) * K + k0 + (colb >> 1)),
                AS3U(&Bs[buf][(p * 4096 + wave * 1024) >> 1]), 16, 0, 0);
        }
    };

    const int nt = K >> 5;
    stage(0, 0);
    __syncthreads();
    int cur = 0;
    for (int t = 0; t < nt; ++t) {
        if (t + 1 < nt) stage(cur ^ 1, (t + 1) * 32);
        const int fr = lane & 15;
        const int kb = (lane >> 4) * 8;
        short8 af[4], bf[4];
        #pragma unroll
        for (int m = 0; m < 4; ++m)
            af[m] = *reinterpret_cast<const short8*>(&As[cur][(wr + m * 16 + fr) * 32 + kb]);
        #pragma unroll
        for (int n = 0; n < 4; ++n)
            bf[n] = *reinterpret_cast<const short8*>(&Bs[cur][(wc + n * 16 + fr) * 32 + kb]);
        #pragma unroll
        for (int m = 0; m < 4; ++m)
            #pragma unroll
            for (int n = 0; n < 4; ++n)
                acc[m][n] = __builtin_amdgcn_mfma_f32_16x16x32_bf16(af[m], bf[n], acc[m][n], 0, 0, 0);
        if (t + 1 < nt) { __syncthreads(); cur ^= 1; }
    }

    const int fr = lane & 15;
    const int r0 = (lane >> 4) * 4;
    #pragma unroll
    for (int n = 0; n < 4; ++n) {
        const int col = n0 + wc + n * 16 + fr;
        const float bv = bias[col];
        #pragma unroll
        for (int m = 0; m < 4; ++m) {
            #pragma unroll
            for (int r = 0; r < 4; ++r) {
                const int row = m0 + wr + m * 16 + r0 + r;
                if (row < M) {
                    float v = acc[m][n][r] + bv;
                    if (RELU) v = fmaxf(v, 0.f);
                    if (OUT_BF16)
                        ((unsigned short*)Cout)[(size_t)row * N + col] = f2bf(v);
                    else
                        ((float*)Cout)[(size_t)row * N + col] = v;
                }
            }
        }
    }
}

// ---------------------------------------------------------------------------
// GEMM (N=256) + bias + residual + LayerNorm, fused. 2-phase double-buffered.
// BM=64, BN=256, BK=32, 512 threads = 8 waves (2 row x 4 col).
// ---------------------------------------------------------------------------
template<int MIRROR>
__global__ __launch_bounds__(512) void gemm_ln(
    const unsigned short* __restrict__ A,
    const unsigned short* __restrict__ BT,
    const float* __restrict__ bias,
    const float* __restrict__ res,
    const float* __restrict__ g,
    const float* __restrict__ beta,
    float* __restrict__ outf,
    unsigned short* __restrict__ out16,
    int M, int K)
{
    __shared__ unsigned short As[2][64 * 32];
    __shared__ unsigned short Bs[2][256 * 32];
    __shared__ float2 sRed[4][64];

    const int tid  = threadIdx.x;
    const int wave = tid >> 6;
    const int lane = tid & 63;
    const int m0 = blockIdx.x * 64;
    const int wr = (wave >> 2) * 32;
    const int wc = (wave & 3) * 64;

    f32x4 acc[2][4] = {};

    auto stage = [&](int buf, int k0) {
        if (tid < 256) {
            const int off  = tid * 16;
            const int row  = off >> 6;
            const int colb = off & 63;
            int ar = m0 + row; ar = (ar < M) ? ar : (M - 1);
            __builtin_amdgcn_global_load_lds(AS1U(A + (size_t)ar * K + k0 + (colb >> 1)),
                AS3U(&As[buf][(wave * 1024) >> 1]), 16, 0, 0);
        }
        #pragma unroll
        for (int p = 0; p < 2; ++p) {
            const int off  = p * 8192 + tid * 16;
            const int row  = off >> 6;
            const int colb = off & 63;
            __builtin_amdgcn_global_load_lds(AS1U(BT + (size_t)row * K + k0 + (colb >> 1)),
                AS3U(&Bs[buf][(p * 8192 + wave * 1024) >> 1]), 16, 0, 0);
        }
    };

    const int nt = K >> 5;
    stage(0, 0);
    __syncthreads();
    int cur = 0;
    for (int t = 0; t < nt; ++t) {
        if (t + 1 < nt) stage(cur ^ 1, (t + 1) * 32);
        const int fr = lane & 15;
        const int kb = (lane >> 4) * 8;
        short8 af[2], bf[4];
        #pragma unroll
        for (int m = 0; m < 2; ++m)
            af[m] = *reinterpret_cast<const short8*>(&As[cur][(wr + m * 16 + fr) * 32 + kb]);
        #pragma unroll
        for (int n = 0; n < 4; ++n)
            bf[n] = *reinterpret_cast<const short8*>(&Bs[cur][(wc + n * 16 + fr) * 32 + kb]);
        #pragma unroll
        for (int m = 0; m < 2; ++m)
            #pragma unroll
            for (int n = 0; n < 4; ++n)
                acc[m][n] = __builtin_amdgcn_mfma_f32_16x16x32_bf16(af[m], bf[n], acc[m][n], 0, 0, 0);
        if (t + 1 < nt) { __syncthreads(); cur ^= 1; }
    }

    const int fr = lane & 15;
    const int r0 = (lane >> 4) * 4;
    float biasv[4], gv[4], bev[4];
    #pragma unroll
    for (int n = 0; n < 4; ++n) {
        const int col = wc + n * 16 + fr;
        biasv[n] = bias[col]; gv[n] = g[col]; bev[n] = beta[col];
    }
    #pragma unroll
    for (int m = 0; m < 2; ++m) {
        #pragma unroll
        for (int r = 0; r < 4; ++r) {
            int row = m0 + wr + m * 16 + r0 + r;
            int rr = (row < M) ? row : (M - 1);
            const float* rp = res + (size_t)rr * 256;
            #pragma unroll
            for (int n = 0; n < 4; ++n)
                acc[m][n][r] += biasv[n] + rp[wc + n * 16 + fr];
        }
    }
    #pragma unroll
    for (int m = 0; m < 2; ++m) {
        #pragma unroll
        for (int r = 0; r < 4; ++r) {
            float sx = 0.f, sxx = 0.f;
            #pragma unroll
            for (int n = 0; n < 4; ++n) { float t = acc[m][n][r]; sx += t; sxx += t * t; }
            #pragma unroll
            for (int mask = 1; mask < 16; mask <<= 1) {
                sx  += __shfl_xor(sx, mask);
                sxx += __shfl_xor(sxx, mask);
            }
            if (fr == 0) sRed[wave & 3][wr + m * 16 + r0 + r] = make_float2(sx, sxx);
        }
    }
    __syncthreads();
    #pragma unroll
    for (int m = 0; m < 2; ++m) {
        #pragma unroll
        for (int r = 0; r < 4; ++r) {
            const int lr = wr + m * 16 + r0 + r;
            float2 a0 = sRed[0][lr], a1 = sRed[1][lr], a2 = sRed[2][lr], a3 = sRed[3][lr];
            const float S  = a0.x + a1.x + a2.x + a3.x;
            const float SS = a0.y + a1.y + a2.y + a3.y;
            const float mean = S * (1.f / 256.f);
            const float var  = SS * (1.f / 256.f) - mean * mean;
            const float rstd = rsqrtf(var + 1e-5f);
            const int row = m0 + lr;
            if (row < M) {
                #pragma unroll
                for (int n = 0; n < 4; ++n) {
                    const int col = wc + n * 16 + fr;
                    const float y = (acc[m][n][r] - mean) * rstd * gv[n] + bev[n];
                    outf[(size_t)row * 256 + col] = y;
                    if (MIRROR) out16[(size_t)row * 256 + col] = f2bf(y);
                }
            }
        }
    }
}

// ---------------------------------------------------------------------------
// Multi-scale deformable attention, XCD-local by head (round-6 layout),
// depth-2 software-pipelined gathers.
// vproj_h: bf16 [b][h][lv][32].  Block = (qc, bh); 4 waves x 8 queries.
// Phase 2: lane (qw, k) gathers 8 B (channels 4k..4k+3) x 4 corners x 16 points,
// prefetching point p+1's 4 loads before consuming point p.
// ---------------------------------------------------------------------------
__global__ __launch_bounds__(256) void msdeform_kernel(
    const unsigned short* __restrict__ vproj_h, const float* __restrict__ offattn,
    const float* __restrict__ refp, unsigned short* __restrict__ msout)
{
    __shared__ int4   sIdx[4][8][17];   // byte offsets (idx*64)
    __shared__ float4 sWgt[4][8][17];

    const int bh = blockIdx.x & 15;          // b*8 + h
    const int qc = blockIdx.x >> 4;
    const int b  = bh >> 3;
    const int h  = bh & 7;
    const int wave = threadIdx.x >> 6;
    const int lane = threadIdx.x & 63;
    const int qw = lane >> 3;                // query within wave
    const int k  = lane & 7;                 // point-pair / channel-quad
    const int lv = qc * 32 + wave * 8 + qw;
    if (lv >= LQ_) return;
    const int bq = b * LQ_ + lv;

    // ---- phase 1: weights & indices ----
    const float4 o4  = *reinterpret_cast<const float4*>(offattn + (size_t)bq * 384 + h * 32 + 4 * k);
    const float2 lg2 = *reinterpret_cast<const float2*>(offattn + (size_t)bq * 384 + 256 + h * 16 + 2 * k);
    const int l = k >> 1;
    const float2 rp  = *reinterpret_cast<const float2*>(refp + (size_t)bq * 8 + 2 * l);

    const float Wf[4] = {106.f, 53.f, 27.f, 14.f};
    const float Hf[4] = {76.f, 38.f, 19.f, 10.f};
    const int   Wi[4] = {106, 53, 27, 14};
    const int   Hi[4] = {76, 38, 19, 10};
    const int   St[4] = {0, 8056, 10070, 10583};

    float mx = fmaxf(lg2.x, lg2.y);
    mx = fmaxf(mx, __shfl_xor(mx, 1));
    mx = fmaxf(mx, __shfl_xor(mx, 2));
    mx = fmaxf(mx, __shfl_xor(mx, 4));
    const float e0 = __expf(lg2.x - mx), e1 = __expf(lg2.y - mx);
    float s = e0 + e1;
    s += __shfl_xor(s, 1); s += __shfl_xor(s, 2); s += __shfl_xor(s, 4);
    const float inv = 1.f / s;

    const int W = Wi[l], H = Hi[l];
    const float Wff = Wf[l], Hff = Hf[l];
    const int base = St[l];

    #pragma unroll
    for (int pp = 0; pp < 2; ++pp) {
        const float ox = pp ? o4.z : o4.x;
        const float oy = pp ? o4.w : o4.y;
        const float aw = (pp ? e1 : e0) * inv;
        const float x = fmaf(rp.x, Wff, ox) - 0.5f;
        const float y = fmaf(rp.y, Hff, oy) - 0.5f;
        const float xf = floorf(x), yf = floorf(y);
        const float fx = x - xf, fy = y - yf;
        const int x0 = (int)xf, y0 = (int)yf;
        const float gx = 1.f - fx, gy = 1.f - fy;
        const bool vx0 = (x0 >= 0) && (x0 < W);
        const bool vx1 = (x0 + 1 >= 0) && (x0 + 1 < W);
        const bool vy0 = (y0 >= 0) && (y0 < H);
        const bool vy1 = (y0 + 1 >= 0) && (y0 + 1 < H);
        const int xc0 = min(max(x0, 0), W - 1);
        const int xc1 = min(max(x0 + 1, 0), W - 1);
        const int yr0 = min(max(y0, 0), H - 1) * W;
        const int yr1 = min(max(y0 + 1, 0), H - 1) * W;
        int4 iv; float4 wv;
        iv.x = (base + yr0 + xc0) << 6;  wv.x = (vx0 && vy0) ? gx * gy * aw : 0.f;
        iv.y = (base + yr0 + xc1) << 6;  wv.y = (vx1 && vy0) ? fx * gy * aw : 0.f;
        iv.z = (base + yr1 + xc0) << 6;  wv.z = (vx0 && vy1) ? gx * fy * aw : 0.f;
        iv.w = (base + yr1 + xc1) << 6;  wv.w = (vx1 && vy1) ? fx * fy * aw : 0.f;
        sIdx[wave][qw][2 * k + pp] = iv;
        sWgt[wave][qw][2 * k + pp] = wv;
    }

    // ---- phase 2: depth-2 pipelined gather ----
    const char* vb = (const char*)(vproj_h + (size_t)bh * LQ_ * 32) + k * 8;
    float4 acc = make_float4(0.f, 0.f, 0.f, 0.f);

    int4 iv0 = sIdx[wave][qw][0];
    uint2 a0 = *reinterpret_cast<const uint2*>(vb + (unsigned)iv0.x);
    uint2 a1 = *reinterpret_cast<const uint2*>(vb + (unsigned)iv0.y);
    uint2 a2 = *reinterpret_cast<const uint2*>(vb + (unsigned)iv0.z);
    uint2 a3 = *reinterpret_cast<const uint2*>(vb + (unsigned)iv0.w);

    #pragma unroll
    for (int p = 0; p < 16; ++p) {
        uint2 b0, b1, b2, b3;
        if (p < 15) {
            const int4 nv = sIdx[wave][qw][p + 1];
            b0 = *reinterpret_cast<const uint2*>(vb + (unsigned)nv.x);
            b1 = *reinterpret_cast<const uint2*>(vb + (unsigned)nv.y);
            b2 = *reinterpret_cast<const uint2*>(vb + (unsigned)nv.z);
            b3 = *reinterpret_cast<const uint2*>(vb + (unsigned)nv.w);
        }
        const float4 wv = sWgt[wave][qw][p];
        acc.x = fmaf(wv.x, bflo(a0.x), acc.x); acc.y = fmaf(wv.x, bfhi(a0.x), acc.y);
        acc.z = fmaf(wv.x, bflo(a0.y), acc.z); acc.w = fmaf(wv.x, bfhi(a0.y), acc.w);
        acc.x = fmaf(wv.y, bflo(a1.x), acc.x); acc.y = fmaf(wv.y, bfhi(a1.x), acc.y);
        acc.z = fmaf(wv.y, bflo(a1.y), acc.z); acc.w = fmaf(wv.y, bfhi(a1.y), acc.w);
        acc.x = fmaf(wv.z, bflo(a2.x), acc.x); acc.y = fmaf(wv.z, bfhi(a2.x), acc.y);
        acc.z = fmaf(wv.z, bflo(a2.y), acc.z); acc.w = fmaf(wv.z, bfhi(a2.y), acc.w);
        acc.x = fmaf(wv.w, bflo(a3.x), acc.x); acc.y = fmaf(wv.w, bfhi(a3.x), acc.y);
        acc.z = fmaf(wv.w, bflo(a3.y), acc.z); acc.w = fmaf(wv.w, bfhi(a3.y), acc.w);
        a0 = b0; a1 = b1; a2 = b2; a3 = b3;
    }
    // channel order within the 8B: [lo0, hi0, lo1, hi1] = ch 4k,4k+1,4k+2,4k+3
    us4 r = { f2bf(acc.x), f2bf(acc.y), f2bf(acc.z), f2bf(acc.w) };
    *reinterpret_cast<us4*>(msout + (size_t)bq * 256 + h * 32 + k * 4) = r;
}

// ---------------------------------------------------------------------------
extern "C" void kernel_launch(void* const* d_in, const int* in_sizes, int n_in,
                              void* d_out, int out_size, void* d_ws, size_t ws_size,
                              hipStream_t stream) {
    const float* query = (const float*)d_in[0];
    const float* qpos  = (const float*)d_in[1];
    const float* value = (const float*)d_in[2];
    const float* refp  = (const float*)d_in[3];
    const float* W_off  = (const float*)d_in[6];
    const float* b_off  = (const float*)d_in[7];
    const float* W_attn = (const float*)d_in[8];
    const float* b_attn = (const float*)d_in[9];
    const float* W_v    = (const float*)d_in[10];
    const float* b_v    = (const float*)d_in[11];
    const float* W_out  = (const float*)d_in[12];
    const float* b_out  = (const float*)d_in[13];
    const float* ln1_g  = (const float*)d_in[14];
    const float* ln1_b  = (const float*)d_in[15];
    const float* W1     = (const float*)d_in[16];
    const float* b1     = (const float*)d_in[17];
    const float* W2     = (const float*)d_in[18];
    const float* b2     = (const float*)d_in[19];
    const float* ln2_g  = (const float*)d_in[20];
    const float* ln2_b  = (const float*)d_in[21];
    float* out = (float*)d_out;

    // ---- workspace layout ----
    unsigned short* WvT   = (unsigned short*)d_ws;
    unsigned short* WoaT  = WvT   + 65536;    // 384 x 256  (off | attn)
    unsigned short* WoutT = WoaT  + 98304;
    unsigned short* W1T   = WoutT + 65536;    // 1024 x 256
    unsigned short* W2T   = W1T   + 262144;   // 256 x 1024
    float* b_oa = (float*)(W2T + 262144);     // 384 f32
    uint8_t* base = (uint8_t*)(b_oa + 384);
    base = (uint8_t*)(((uintptr_t)base + 255) & ~(uintptr_t)255);

    const size_t A = (size_t)M_ * D_;
    unsigned short* R_v16  = (unsigned short*)base;          // value bf16 -> q1 bf16 mirror
    unsigned short* R_q16  = R_v16 + A;                      // q bf16 -> ms16
    unsigned short* R_vph  = R_q16 + A;                      // vproj bf16 head-major
    float* R_oa  = (float*)(R_vph + A);                      // off|attn (M,384)
    float* R_q1  = R_oa + (size_t)M_ * 384;                  // q1 f32
    unsigned short* R_h16 = (unsigned short*)(R_q1 + A);     // FFN hidden bf16 (M,1024)

    const dim3 blk(256);
    auto cdiv = [](size_t a, size_t b) { return (unsigned)((a + b - 1) / b); };

    const int n4 = (int)(A / 4);
    prep_kernel<<<cdiv(754048 + 2 * (size_t)n4, 256), blk, 0, stream>>>(
        W_v, W_off, W_attn, W_out, W1, W2, b_off, b_attn, value, query, qpos,
        WvT, WoaT, WoutT, W1T, W2T, b_oa, R_v16, R_q16, n4);

    const unsigned MT = (M_ + 127) / 128;   // 168
    // vproj (head-major bf16) + off|attn (f32), one dispatch
    gemm_pre<<<dim3(5, MT), blk, 0, stream>>>(
        R_v16, R_q16, WvT, WoaT, b_v, b_oa, R_vph, R_oa);
    // deformable attention -> ms16 (overwrites R_q16, dead)
    const unsigned nQC = cdiv(LQ_, 32);   // 336
    msdeform_kernel<<<dim3(nQC * 16), blk, 0, stream>>>(R_vph, R_oa, refp, R_q16);
    // q1 = LN(query + ms16@WoutT^T + b_out): f32 -> R_q1, bf16 -> R_v16 (dead)
    gemm_ln<1><<<dim3(cdiv(M_, 64)), dim3(512), 0, stream>>>(
        R_q16, WoutT, b_out, query, ln1_g, ln1_b, R_q1, R_v16, M_, 256);
    // h = relu(q1b @ W1T^T) bf16
    gemm_mfma<1, 1><<<dim3(8, MT), blk, 0, stream>>>(R_v16, W1T, b1, R_h16, M_, 1024, 256);
    // out = LN(q1 + h@W2T^T + b2)
    gemm_ln<0><<<dim3(cdiv(M_, 64)), dim3(512), 0, stream>>>(
        R_h16, W2T, b2, R_q1, ln2_g, ln2_b, out, nullptr, M_, 1024);
}

// Round 9
// 167.709 us; speedup vs baseline: 1.4826x; 1.0680x over previous
//
#include <hip/hip_runtime.h>
#include <math.h>

#define B_   2
#define LQ_  10723
#define D_   256
#define NH_  8
#define HD_  32
#define NL_  4
#define NP_  4
#define DFF_ 1024
#define M_   (B_ * LQ_)   // 21446

typedef __attribute__((ext_vector_type(4))) float f32x4;
typedef __attribute__((ext_vector_type(8))) short short8;
typedef __attribute__((ext_vector_type(4))) unsigned short us4;
typedef __attribute__((ext_vector_type(8))) unsigned short us8;
typedef __attribute__((ext_vector_type(4))) unsigned int u32x4;

__device__ __forceinline__ unsigned short f2bf(float f) {
    union { float f; unsigned int u; } x; x.f = f;
    unsigned int r = x.u + 0x7FFF + ((x.u >> 16) & 1);   // RNE
    return (unsigned short)(r >> 16);
}
__device__ __forceinline__ float bflo(unsigned int u) {
    union { unsigned int u; float f; } x; x.u = u << 16; return x.f;
}
__device__ __forceinline__ float bfhi(unsigned int u) {
    union { unsigned int u; float f; } x; x.u = u & 0xffff0000u; return x.f;
}

#define AS3U(p) ((__attribute__((address_space(3))) unsigned int*)(uintptr_t)(p))
#define AS1U(p) ((const __attribute__((address_space(1))) unsigned int*)(uintptr_t)(p))

// ---------------------------------------------------------------------------
// Fused prep: weight transpose/convert + bias concat + activation convert.
// ---------------------------------------------------------------------------
__global__ __launch_bounds__(256) void prep_kernel(
    const float* __restrict__ Wv, const float* __restrict__ Woff,
    const float* __restrict__ Wattn, const float* __restrict__ Wout,
    const float* __restrict__ W1, const float* __restrict__ W2,
    const float* __restrict__ b_off, const float* __restrict__ b_attn,
    const float* __restrict__ value, const float* __restrict__ query,
    const float* __restrict__ qpos,
    unsigned short* __restrict__ WvT, unsigned short* __restrict__ WoaT,
    unsigned short* __restrict__ WoutT, unsigned short* __restrict__ W1T,
    unsigned short* __restrict__ W2T, float* __restrict__ b_oa,
    unsigned short* __restrict__ v16, unsigned short* __restrict__ q16, int n4)
{
    int idx = blockIdx.x * 256 + threadIdx.x;
    if (idx < 65536) {
        int n = idx >> 8, k = idx & 255;
        WvT[idx] = f2bf(Wv[k * 256 + n]);
    } else if (idx < 163840) {
        int l = idx - 65536; int n = l >> 8, k = l & 255;
        WoaT[l] = f2bf(n < 256 ? Woff[k * 256 + n] : Wattn[k * 128 + (n - 256)]);
    } else if (idx < 229376) {
        int l = idx - 163840; int n = l >> 8, k = l & 255;
        WoutT[l] = f2bf(Wout[k * 256 + n]);
    } else if (idx < 491520) {
        int l = idx - 229376; int n = l >> 8, k = l & 255;
        W1T[l] = f2bf(W1[k * 1024 + n]);
    } else if (idx < 753664) {
        int l = idx - 491520; int n = l >> 10, k = l & 1023;
        W2T[l] = f2bf(W2[k * 256 + n]);
    } else if (idx < 754048) {
        int l = idx - 753664;
        b_oa[l] = (l < 256) ? b_off[l] : b_attn[l - 256];
    } else if (idx < 754048 + n4) {
        int i = idx - 754048;
        float4 v = reinterpret_cast<const float4*>(value)[i];
        us4 r = { f2bf(v.x), f2bf(v.y), f2bf(v.z), f2bf(v.w) };
        reinterpret_cast<us4*>(v16)[i] = r;
    } else if (idx < 754048 + 2 * n4) {
        int j = idx - 754048 - n4;
        float4 va = reinterpret_cast<const float4*>(query)[j];
        float4 vb = reinterpret_cast<const float4*>(qpos)[j];
        us4 r = { f2bf(va.x + vb.x), f2bf(va.y + vb.y), f2bf(va.z + vb.z), f2bf(va.w + vb.w) };
        reinterpret_cast<us4*>(q16)[j] = r;
    }
}

// ---------------------------------------------------------------------------
// Fused vproj + off/attn GEMM dispatch. 128x128 tile, BK=32, K=256, 2-phase.
// blockIdx.x < 2 : vproj = v16 @ WvT^T + b_v -> bf16 head-major [b][h][lv][32]
// blockIdx.x >= 2: oa    = q16 @ WoaT^T + b_oa -> f32 (M,384)
// ---------------------------------------------------------------------------
__global__ __launch_bounds__(256) void gemm_pre(
    const unsigned short* __restrict__ v16, const unsigned short* __restrict__ q16,
    const unsigned short* __restrict__ WvT, const unsigned short* __restrict__ WoaT,
    const float* __restrict__ b_v, const float* __restrict__ b_oa,
    unsigned short* __restrict__ vph, float* __restrict__ oa)
{
    __shared__ unsigned short As[2][128 * 32];
    __shared__ unsigned short Bs[2][128 * 32];

    const bool is_v = (blockIdx.x < 2);
    const unsigned short* A  = is_v ? v16 : q16;
    const unsigned short* BT = is_v ? WvT : WoaT;
    const float* bias = is_v ? b_v : b_oa;
    const int n0 = (is_v ? (int)blockIdx.x : (int)blockIdx.x - 2) * 128;
    const int K = 256;

    const int tid  = threadIdx.x;
    const int wave = tid >> 6;
    const int lane = tid & 63;
    const int m0 = blockIdx.y * 128;
    const int wr = (wave >> 1) * 64;
    const int wc = (wave & 1) * 64;

    f32x4 acc[4][4] = {};
    const int soff = wave * 1024 + lane * 16;

    auto stage = [&](int buf, int k0) {
        #pragma unroll
        for (int p = 0; p < 2; ++p) {
            const int off  = p * 4096 + soff;
            const int row  = off >> 6;
            const int colb = off & 63;
            int ar = m0 + row; ar = (ar < M_) ? ar : (M_ - 1);
            __builtin_amdgcn_global_load_lds(AS1U(A + (size_t)ar * K + k0 + (colb >> 1)),
                AS3U(&As[buf][(p * 4096 + wave * 1024) >> 1]), 16, 0, 0);
            __builtin_amdgcn_global_load_lds(AS1U(BT + (size_t)(n0 + row) * K + k0 + (colb >> 1)),
                AS3U(&Bs[buf][(p * 4096 + wave * 1024) >> 1]), 16, 0, 0);
        }
    };

    stage(0, 0);
    __syncthreads();
    int cur = 0;
    for (int t = 0; t < 8; ++t) {
        if (t + 1 < 8) stage(cur ^ 1, (t + 1) * 32);
        const int fr = lane & 15;
        const int kb = (lane >> 4) * 8;
        short8 af[4], bf[4];
        #pragma unroll
        for (int m = 0; m < 4; ++m)
            af[m] = *reinterpret_cast<const short8*>(&As[cur][(wr + m * 16 + fr) * 32 + kb]);
        #pragma unroll
        for (int n = 0; n < 4; ++n)
            bf[n] = *reinterpret_cast<const short8*>(&Bs[cur][(wc + n * 16 + fr) * 32 + kb]);
        #pragma unroll
        for (int m = 0; m < 4; ++m)
            #pragma unroll
            for (int n = 0; n < 4; ++n)
                acc[m][n] = __builtin_amdgcn_mfma_f32_16x16x32_bf16(af[m], bf[n], acc[m][n], 0, 0, 0);
        if (t + 1 < 8) { __syncthreads(); cur ^= 1; }
    }

    const int fr = lane & 15;
    const int r0 = (lane >> 4) * 4;
    #pragma unroll
    for (int n = 0; n < 4; ++n) {
        const int col = n0 + wc + n * 16 + fr;
        const float bv = bias[col];
        #pragma unroll
        for (int m = 0; m < 4; ++m) {
            #pragma unroll
            for (int r = 0; r < 4; ++r) {
                const int row = m0 + wr + m * 16 + r0 + r;
                if (row < M_) {
                    float v = acc[m][n][r] + bv;
                    if (is_v) {
                        // head-major: [b][h][lv][32]
                        const int bb = (row >= LQ_) ? 1 : 0;
                        const int lv = row - bb * LQ_;
                        const int hh = col >> 5, dd = col & 31;
                        vph[(((size_t)bb * NH_ + hh) * LQ_ + lv) * 32 + dd] = f2bf(v);
                    } else {
                        oa[(size_t)row * 384 + col] = v;
                    }
                }
            }
        }
    }
}

// ---------------------------------------------------------------------------
// Generic MFMA bf16 GEMM (FFN1 use): 128x128 tile, BK=32, 2-phase dbuf.
// ---------------------------------------------------------------------------
template<int RELU, int OUT_BF16>
__global__ __launch_bounds__(256) void gemm_mfma(
    const unsigned short* __restrict__ A,
    const unsigned short* __restrict__ BT,
    const float* __restrict__ bias,
    void* __restrict__ Cout,
    int M, int N, int K)
{
    __shared__ unsigned short As[2][128 * 32];
    __shared__ unsigned short Bs[2][128 * 32];

    const int tid  = threadIdx.x;
    const int wave = tid >> 6;
    const int lane = tid & 63;
    const int m0 = blockIdx.y * 128;
    const int n0 = blockIdx.x * 128;
    const int wr = (wave >> 1) * 64;
    const int wc = (wave & 1) * 64;

    f32x4 acc[4][4] = {};
    const int soff = wave * 1024 + lane * 16;

    auto stage = [&](int buf, int k0) {
        #pragma unroll
        for (int p = 0; p < 2; ++p) {
            const int off  = p * 4096 + soff;
            const int row  = off >> 6;
            const int colb = off & 63;
            int ar = m0 + row; ar = (ar < M) ? ar : (M - 1);
            __builtin_amdgcn_global_load_lds(AS1U(A + (size_t)ar * K + k0 + (colb >> 1)),
                AS3U(&As[buf][(p * 4096 + wave * 1024) >> 1]), 16, 0, 0);
            __builtin_amdgcn_global_load_lds(AS1U(BT + (size_t)(n0 + row) * K + k0 + (colb >> 1)),
                AS3U(&Bs[buf][(p * 4096 + wave * 1024) >> 1]), 16, 0, 0);
        }
    };

    const int nt = K >> 5;
    stage(0, 0);
    __syncthreads();
    int cur = 0;
    for (int t = 0; t < nt; ++t) {
        if (t + 1 < nt) stage(cur ^ 1, (t + 1) * 32);
        const int fr = lane & 15;
        const int kb = (lane >> 4) * 8;
        short8 af[4], bf[4];
        #pragma unroll
        for (int m = 0; m < 4; ++m)
            af[m] = *reinterpret_cast<const short8*>(&As[cur][(wr + m * 16 + fr) * 32 + kb]);
        #pragma unroll
        for (int n = 0; n < 4; ++n)
            bf[n] = *reinterpret_cast<const short8*>(&Bs[cur][(wc + n * 16 + fr) * 32 + kb]);
        #pragma unroll
        for (int m = 0; m < 4; ++m)
            #pragma unroll
            for (int n = 0; n < 4; ++n)
                acc[m][n] = __builtin_amdgcn_mfma_f32_16x16x32_bf16(af[m], bf[n], acc[m][n], 0, 0, 0);
        if (t + 1 < nt) { __syncthreads(); cur ^= 1; }
    }

    const int fr = lane & 15;
    const int r0 = (lane >> 4) * 4;
    #pragma unroll
    for (int n = 0; n < 4; ++n) {
        const int col = n0 + wc + n * 16 + fr;
        const float bv = bias[col];
        #pragma unroll
        for (int m = 0; m < 4; ++m) {
            #pragma unroll
            for (int r = 0; r < 4; ++r) {
                const int row = m0 + wr + m * 16 + r0 + r;
                if (row < M) {
                    float v = acc[m][n][r] + bv;
                    if (RELU) v = fmaxf(v, 0.f);
                    if (OUT_BF16)
                        ((unsigned short*)Cout)[(size_t)row * N + col] = f2bf(v);
                    else
                        ((float*)Cout)[(size_t)row * N + col] = v;
                }
            }
        }
    }
}

// ---------------------------------------------------------------------------
// GEMM (N=256) + bias + residual + LayerNorm, fused. 2-phase double-buffered.
// BM=64, BN=256, BK=32, 512 threads = 8 waves (2 row x 4 col).
// ---------------------------------------------------------------------------
template<int MIRROR>
__global__ __launch_bounds__(512) void gemm_ln(
    const unsigned short* __restrict__ A,
    const unsigned short* __restrict__ BT,
    const float* __restrict__ bias,
    const float* __restrict__ res,
    const float* __restrict__ g,
    const float* __restrict__ beta,
    float* __restrict__ outf,
    unsigned short* __restrict__ out16,
    int M, int K)
{
    __shared__ unsigned short As[2][64 * 32];
    __shared__ unsigned short Bs[2][256 * 32];
    __shared__ float2 sRed[4][64];

    const int tid  = threadIdx.x;
    const int wave = tid >> 6;
    const int lane = tid & 63;
    const int m0 = blockIdx.x * 64;
    const int wr = (wave >> 2) * 32;
    const int wc = (wave & 3) * 64;

    f32x4 acc[2][4] = {};

    auto stage = [&](int buf, int k0) {
        if (tid < 256) {
            const int off  = tid * 16;
            const int row  = off >> 6;
            const int colb = off & 63;
            int ar = m0 + row; ar = (ar < M) ? ar : (M - 1);
            __builtin_amdgcn_global_load_lds(AS1U(A + (size_t)ar * K + k0 + (colb >> 1)),
                AS3U(&As[buf][(wave * 1024) >> 1]), 16, 0, 0);
        }
        #pragma unroll
        for (int p = 0; p < 2; ++p) {
            const int off  = p * 8192 + tid * 16;
            const int row  = off >> 6;
            const int colb = off & 63;
            __builtin_amdgcn_global_load_lds(AS1U(BT + (size_t)row * K + k0 + (colb >> 1)),
                AS3U(&Bs[buf][(p * 8192 + wave * 1024) >> 1]), 16, 0, 0);
        }
    };

    const int nt = K >> 5;
    stage(0, 0);
    __syncthreads();
    int cur = 0;
    for (int t = 0; t < nt; ++t) {
        if (t + 1 < nt) stage(cur ^ 1, (t + 1) * 32);
        const int fr = lane & 15;
        const int kb = (lane >> 4) * 8;
        short8 af[2], bf[4];
        #pragma unroll
        for (int m = 0; m < 2; ++m)
            af[m] = *reinterpret_cast<const short8*>(&As[cur][(wr + m * 16 + fr) * 32 + kb]);
        #pragma unroll
        for (int n = 0; n < 4; ++n)
            bf[n] = *reinterpret_cast<const short8*>(&Bs[cur][(wc + n * 16 + fr) * 32 + kb]);
        #pragma unroll
        for (int m = 0; m < 2; ++m)
            #pragma unroll
            for (int n = 0; n < 4; ++n)
                acc[m][n] = __builtin_amdgcn_mfma_f32_16x16x32_bf16(af[m], bf[n], acc[m][n], 0, 0, 0);
        if (t + 1 < nt) { __syncthreads(); cur ^= 1; }
    }

    const int fr = lane & 15;
    const int r0 = (lane >> 4) * 4;
    float biasv[4], gv[4], bev[4];
    #pragma unroll
    for (int n = 0; n < 4; ++n) {
        const int col = wc + n * 16 + fr;
        biasv[n] = bias[col]; gv[n] = g[col]; bev[n] = beta[col];
    }
    #pragma unroll
    for (int m = 0; m < 2; ++m) {
        #pragma unroll
        for (int r = 0; r < 4; ++r) {
            int row = m0 + wr + m * 16 + r0 + r;
            int rr = (row < M) ? row : (M - 1);
            const float* rp = res + (size_t)rr * 256;
            #pragma unroll
            for (int n = 0; n < 4; ++n)
                acc[m][n][r] += biasv[n] + rp[wc + n * 16 + fr];
        }
    }
    #pragma unroll
    for (int m = 0; m < 2; ++m) {
        #pragma unroll
        for (int r = 0; r < 4; ++r) {
            float sx = 0.f, sxx = 0.f;
            #pragma unroll
            for (int n = 0; n < 4; ++n) { float t = acc[m][n][r]; sx += t; sxx += t * t; }
            #pragma unroll
            for (int mask = 1; mask < 16; mask <<= 1) {
                sx  += __shfl_xor(sx, mask);
                sxx += __shfl_xor(sxx, mask);
            }
            if (fr == 0) sRed[wave & 3][wr + m * 16 + r0 + r] = make_float2(sx, sxx);
        }
    }
    __syncthreads();
    #pragma unroll
    for (int m = 0; m < 2; ++m) {
        #pragma unroll
        for (int r = 0; r < 4; ++r) {
            const int lr = wr + m * 16 + r0 + r;
            float2 a0 = sRed[0][lr], a1 = sRed[1][lr], a2 = sRed[2][lr], a3 = sRed[3][lr];
            const float S  = a0.x + a1.x + a2.x + a3.x;
            const float SS = a0.y + a1.y + a2.y + a3.y;
            const float mean = S * (1.f / 256.f);
            const float var  = SS * (1.f / 256.f) - mean * mean;
            const float rstd = rsqrtf(var + 1e-5f);
            const int row = m0 + lr;
            if (row < M) {
                #pragma unroll
                for (int n = 0; n < 4; ++n) {
                    const int col = wc + n * 16 + fr;
                    const float y = (acc[m][n][r] - mean) * rstd * gv[n] + bev[n];
                    outf[(size_t)row * 256 + col] = y;
                    if (MIRROR) out16[(size_t)row * 256 + col] = f2bf(y);
                }
            }
        }
    }
}

// ---------------------------------------------------------------------------
// Multi-scale deformable attention, XCD-local by head.
// Lane remap vs round 6: 4 lanes/query x 16 B (was 8 x 8 B) -> address count
// halves while each corner's 64 B line is still fully covered by the 4-lane
// group (line sharing preserved; round-7 lesson).
// vproj_h: bf16 [b][h][lv][32].  Block = (qc, bh); 4 waves x 16 queries.
// Phase 1: lane (qq, j): level j's 4 points for query qq (softmax over 4-lane group).
// Phase 2: lane (qq, j): channels 8j..8j+7, 16 points x 4 corners x 16 B, depth-2 pipe.
// ---------------------------------------------------------------------------
__global__ __launch_bounds__(256) void msdeform_kernel(
    const unsigned short* __restrict__ vproj_h, const float* __restrict__ offattn,
    const float* __restrict__ refp, unsigned short* __restrict__ msout)
{
    __shared__ int4   sIdx[4][16][17];   // [wave][query][point] word-offsets*64
    __shared__ float4 sWgt[4][16][17];

    const int bh = blockIdx.x & 15;          // b*8 + h
    const int qc = blockIdx.x >> 4;
    const int b  = bh >> 3;
    const int h  = bh & 7;
    const int wave = threadIdx.x >> 6;
    const int lane = threadIdx.x & 63;
    const int qq = lane >> 2;                // query within wave (0..15)
    const int j  = lane & 3;                 // level (ph1) / channel-octet (ph2)
    const int lv = qc * 64 + wave * 16 + qq;
    if (lv >= LQ_) return;
    const int bq = b * LQ_ + lv;

    // ---- phase 1: level j, points 4j..4j+3 ----
    const float4 oA = *reinterpret_cast<const float4*>(offattn + (size_t)bq * 384 + h * 32 + 8 * j);
    const float4 oB = *reinterpret_cast<const float4*>(offattn + (size_t)bq * 384 + h * 32 + 8 * j + 4);
    const float4 lg = *reinterpret_cast<const float4*>(offattn + (size_t)bq * 384 + 256 + h * 16 + 4 * j);
    const float2 rp = *reinterpret_cast<const float2*>(refp + (size_t)bq * 8 + 2 * j);

    const float Wf[4] = {106.f, 53.f, 27.f, 14.f};
    const float Hf[4] = {76.f, 38.f, 19.f, 10.f};
    const int   Wi[4] = {106, 53, 27, 14};
    const int   Hi[4] = {76, 38, 19, 10};
    const int   St[4] = {0, 8056, 10070, 10583};

    float mx = fmaxf(fmaxf(lg.x, lg.y), fmaxf(lg.z, lg.w));
    mx = fmaxf(mx, __shfl_xor(mx, 1));
    mx = fmaxf(mx, __shfl_xor(mx, 2));
    const float e0 = __expf(lg.x - mx), e1 = __expf(lg.y - mx);
    const float e2 = __expf(lg.z - mx), e3 = __expf(lg.w - mx);
    float s = e0 + e1 + e2 + e3;
    s += __shfl_xor(s, 1); s += __shfl_xor(s, 2);
    const float inv = 1.f / s;

    const int W = Wi[j], H = Hi[j];
    const float Wff = Wf[j], Hff = Hf[j];
    const int base = St[j];
    const float oxs[4] = {oA.x, oA.z, oB.x, oB.z};
    const float oys[4] = {oA.y, oA.w, oB.y, oB.w};
    const float ews[4] = {e0, e1, e2, e3};

    #pragma unroll
    for (int i = 0; i < 4; ++i) {
        const float aw = ews[i] * inv;
        const float x = fmaf(rp.x, Wff, oxs[i]) - 0.5f;
        const float y = fmaf(rp.y, Hff, oys[i]) - 0.5f;
        const float xf = floorf(x), yf = floorf(y);
        const float fx = x - xf, fy = y - yf;
        const int x0 = (int)xf, y0 = (int)yf;
        const float gx = 1.f - fx, gy = 1.f - fy;
        const bool vx0 = (x0 >= 0) && (x0 < W);
        const bool vx1 = (x0 + 1 >= 0) && (x0 + 1 < W);
        const bool vy0 = (y0 >= 0) && (y0 < H);
        const bool vy1 = (y0 + 1 >= 0) && (y0 + 1 < H);
        const int xc0 = min(max(x0, 0), W - 1);
        const int xc1 = min(max(x0 + 1, 0), W - 1);
        const int yr0 = min(max(y0, 0), H - 1) * W;
        const int yr1 = min(max(y0 + 1, 0), H - 1) * W;
        int4 iv; float4 wv;
        iv.x = (base + yr0 + xc0) << 6;  wv.x = (vx0 && vy0) ? gx * gy * aw : 0.f;
        iv.y = (base + yr0 + xc1) << 6;  wv.y = (vx1 && vy0) ? fx * gy * aw : 0.f;
        iv.z = (base + yr1 + xc0) << 6;  wv.z = (vx0 && vy1) ? gx * fy * aw : 0.f;
        iv.w = (base + yr1 + xc1) << 6;  wv.w = (vx1 && vy1) ? fx * fy * aw : 0.f;
        sIdx[wave][qq][4 * j + i] = iv;
        sWgt[wave][qq][4 * j + i] = wv;
    }

    // ---- phase 2: depth-2 pipelined gather, 16 B/lane/corner ----
    const char* vb = (const char*)(vproj_h + (size_t)bh * LQ_ * 32) + j * 16;
    f32x4 accA = {0.f, 0.f, 0.f, 0.f};
    f32x4 accB = {0.f, 0.f, 0.f, 0.f};

    int4 iv0 = sIdx[wave][qq][0];
    u32x4 a0 = *reinterpret_cast<const u32x4*>(vb + (unsigned)iv0.x);
    u32x4 a1 = *reinterpret_cast<const u32x4*>(vb + (unsigned)iv0.y);
    u32x4 a2 = *reinterpret_cast<const u32x4*>(vb + (unsigned)iv0.z);
    u32x4 a3 = *reinterpret_cast<const u32x4*>(vb + (unsigned)iv0.w);

    #pragma unroll
    for (int p = 0; p < 16; ++p) {
        u32x4 b0, b1, b2, b3;
        if (p < 15) {
            const int4 nv = sIdx[wave][qq][p + 1];
            b0 = *reinterpret_cast<const u32x4*>(vb + (unsigned)nv.x);
            b1 = *reinterpret_cast<const u32x4*>(vb + (unsigned)nv.y);
            b2 = *reinterpret_cast<const u32x4*>(vb + (unsigned)nv.z);
            b3 = *reinterpret_cast<const u32x4*>(vb + (unsigned)nv.w);
        }
        const float4 wv = sWgt[wave][qq][p];
        accA[0] = fmaf(wv.x, bflo(a0.x), accA[0]); accA[1] = fmaf(wv.x, bfhi(a0.x), accA[1]);
        accA[2] = fmaf(wv.x, bflo(a0.y), accA[2]); accA[3] = fmaf(wv.x, bfhi(a0.y), accA[3]);
        accB[0] = fmaf(wv.x, bflo(a0.z), accB[0]); accB[1] = fmaf(wv.x, bfhi(a0.z), accB[1]);
        accB[2] = fmaf(wv.x, bflo(a0.w), accB[2]); accB[3] = fmaf(wv.x, bfhi(a0.w), accB[3]);
        accA[0] = fmaf(wv.y, bflo(a1.x), accA[0]); accA[1] = fmaf(wv.y, bfhi(a1.x), accA[1]);
        accA[2] = fmaf(wv.y, bflo(a1.y), accA[2]); accA[3] = fmaf(wv.y, bfhi(a1.y), accA[3]);
        accB[0] = fmaf(wv.y, bflo(a1.z), accB[0]); accB[1] = fmaf(wv.y, bfhi(a1.z), accB[1]);
        accB[2] = fmaf(wv.y, bflo(a1.w), accB[2]); accB[3] = fmaf(wv.y, bfhi(a1.w), accB[3]);
        accA[0] = fmaf(wv.z, bflo(a2.x), accA[0]); accA[1] = fmaf(wv.z, bfhi(a2.x), accA[1]);
        accA[2] = fmaf(wv.z, bflo(a2.y), accA[2]); accA[3] = fmaf(wv.z, bfhi(a2.y), accA[3]);
        accB[0] = fmaf(wv.z, bflo(a2.z), accB[0]); accB[1] = fmaf(wv.z, bfhi(a2.z), accB[1]);
        accB[2] = fmaf(wv.z, bflo(a2.w), accB[2]); accB[3] = fmaf(wv.z, bfhi(a2.w), accB[3]);
        accA[0] = fmaf(wv.w, bflo(a3.x), accA[0]); accA[1] = fmaf(wv.w, bfhi(a3.x), accA[1]);
        accA[2] = fmaf(wv.w, bflo(a3.y), accA[2]); accA[3] = fmaf(wv.w, bfhi(a3.y), accA[3]);
        accB[0] = fmaf(wv.w, bflo(a3.z), accB[0]); accB[1] = fmaf(wv.w, bfhi(a3.z), accB[1]);
        accB[2] = fmaf(wv.w, bflo(a3.w), accB[2]); accB[3] = fmaf(wv.w, bfhi(a3.w), accB[3]);
        a0 = b0; a1 = b1; a2 = b2; a3 = b3;
    }
    // channels 8j..8j+7 (lo/hi pairs within each dword)
    us8 r = { f2bf(accA[0]), f2bf(accA[1]), f2bf(accA[2]), f2bf(accA[3]),
              f2bf(accB[0]), f2bf(accB[1]), f2bf(accB[2]), f2bf(accB[3]) };
    *reinterpret_cast<us8*>(msout + (size_t)bq * 256 + h * 32 + j * 8) = r;
}

// ---------------------------------------------------------------------------
extern "C" void kernel_launch(void* const* d_in, const int* in_sizes, int n_in,
                              void* d_out, int out_size, void* d_ws, size_t ws_size,
                              hipStream_t stream) {
    const float* query = (const float*)d_in[0];
    const float* qpos  = (const float*)d_in[1];
    const float* value = (const float*)d_in[2];
    const float* refp  = (const float*)d_in[3];
    const float* W_off  = (const float*)d_in[6];
    const float* b_off  = (const float*)d_in[7];
    const float* W_attn = (const float*)d_in[8];
    const float* b_attn = (const float*)d_in[9];
    const float* W_v    = (const float*)d_in[10];
    const float* b_v    = (const float*)d_in[11];
    const float* W_out  = (const float*)d_in[12];
    const float* b_out  = (const float*)d_in[13];
    const float* ln1_g  = (const float*)d_in[14];
    const float* ln1_b  = (const float*)d_in[15];
    const float* W1     = (const float*)d_in[16];
    const float* b1     = (const float*)d_in[17];
    const float* W2     = (const float*)d_in[18];
    const float* b2     = (const float*)d_in[19];
    const float* ln2_g  = (const float*)d_in[20];
    const float* ln2_b  = (const float*)d_in[21];
    float* out = (float*)d_out;

    // ---- workspace layout ----
    unsigned short* WvT   = (unsigned short*)d_ws;
    unsigned short* WoaT  = WvT   + 65536;    // 384 x 256  (off | attn)
    unsigned short* WoutT = WoaT  + 98304;
    unsigned short* W1T   = WoutT + 65536;    // 1024 x 256
    unsigned short* W2T   = W1T   + 262144;   // 256 x 1024
    float* b_oa = (float*)(W2T + 262144);     // 384 f32
    uint8_t* base = (uint8_t*)(b_oa + 384);
    base = (uint8_t*)(((uintptr_t)base + 255) & ~(uintptr_t)255);

    const size_t A = (size_t)M_ * D_;
    unsigned short* R_v16  = (unsigned short*)base;          // value bf16 -> q1 bf16 mirror
    unsigned short* R_q16  = R_v16 + A;                      // q bf16 -> ms16
    unsigned short* R_vph  = R_q16 + A;                      // vproj bf16 head-major
    float* R_oa  = (float*)(R_vph + A);                      // off|attn (M,384)
    float* R_q1  = R_oa + (size_t)M_ * 384;                  // q1 f32
    unsigned short* R_h16 = (unsigned short*)(R_q1 + A);     // FFN hidden bf16 (M,1024)

    const dim3 blk(256);
    auto cdiv = [](size_t a, size_t b) { return (unsigned)((a + b - 1) / b); };

    const int n4 = (int)(A / 4);
    prep_kernel<<<cdiv(754048 + 2 * (size_t)n4, 256), blk, 0, stream>>>(
        W_v, W_off, W_attn, W_out, W1, W2, b_off, b_attn, value, query, qpos,
        WvT, WoaT, WoutT, W1T, W2T, b_oa, R_v16, R_q16, n4);

    const unsigned MT = (M_ + 127) / 128;   // 168
    // vproj (head-major bf16) + off|attn (f32), one dispatch
    gemm_pre<<<dim3(5, MT), blk, 0, stream>>>(
        R_v16, R_q16, WvT, WoaT, b_v, b_oa, R_vph, R_oa);
    // deformable attention -> ms16 (overwrites R_q16, dead)
    const unsigned nQC = cdiv(LQ_, 64);   // 168
    msdeform_kernel<<<dim3(nQC * 16), blk, 0, stream>>>(R_vph, R_oa, refp, R_q16);
    // q1 = LN(query + ms16@WoutT^T + b_out): f32 -> R_q1, bf16 -> R_v16 (dead)
    gemm_ln<1><<<dim3(cdiv(M_, 64)), dim3(512), 0, stream>>>(
        R_q16, WoutT, b_out, query, ln1_g, ln1_b, R_q1, R_v16, M_, 256);
    // h = relu(q1b @ W1T^T) bf16
    gemm_mfma<1, 1><<<dim3(8, MT), blk, 0, stream>>>(R_v16, W1T, b1, R_h16, M_, 1024, 256);
    // out = LN(q1 + h@W2T^T + b2)
    gemm_ln<0><<<dim3(cdiv(M_, 64)), dim3(512), 0, stream>>>(
        R_h16, W2T, b2, R_q1, ln2_g, ln2_b, out, nullptr, M_, 1024);
}

// Round 10
// 144.854 us; speedup vs baseline: 1.7166x; 1.1578x over previous
//
#include <hip/hip_runtime.h>
#include <math.h>

#define B_   2
#define LQ_  10723
#define D_   256
#define NH_  8
#define HD_  32
#define NL_  4
#define NP_  4
#define DFF_ 1024
#define M_   (B_ * LQ_)   // 21446

typedef __attribute__((ext_vector_type(4))) float f32x4;
typedef __attribute__((ext_vector_type(8))) short short8;
typedef __attribute__((ext_vector_type(4))) unsigned short us4;
typedef __attribute__((ext_vector_type(8))) unsigned short us8;
typedef __attribute__((ext_vector_type(4))) unsigned int u32x4;

__device__ __forceinline__ unsigned short f2bf(float f) {
    union { float f; unsigned int u; } x; x.f = f;
    unsigned int r = x.u + 0x7FFF + ((x.u >> 16) & 1);   // RNE
    return (unsigned short)(r >> 16);
}
__device__ __forceinline__ float bflo(unsigned int u) {
    union { unsigned int u; float f; } x; x.u = u << 16; return x.f;
}
__device__ __forceinline__ float bfhi(unsigned int u) {
    union { unsigned int u; float f; } x; x.u = u & 0xffff0000u; return x.f;
}

#define AS3U(p) ((__attribute__((address_space(3))) unsigned int*)(uintptr_t)(p))
#define AS1U(p) ((const __attribute__((address_space(1))) unsigned int*)(uintptr_t)(p))

// ---------------------------------------------------------------------------
// Fused prep: weight transpose/convert + bias concat + activation convert.
// ---------------------------------------------------------------------------
__global__ __launch_bounds__(256) void prep_kernel(
    const float* __restrict__ Wv, const float* __restrict__ Woff,
    const float* __restrict__ Wattn, const float* __restrict__ Wout,
    const float* __restrict__ W1, const float* __restrict__ W2,
    const float* __restrict__ b_off, const float* __restrict__ b_attn,
    const float* __restrict__ value, const float* __restrict__ query,
    const float* __restrict__ qpos,
    unsigned short* __restrict__ WvT, unsigned short* __restrict__ WoaT,
    unsigned short* __restrict__ WoutT, unsigned short* __restrict__ W1T,
    unsigned short* __restrict__ W2T, float* __restrict__ b_oa,
    unsigned short* __restrict__ v16, unsigned short* __restrict__ q16, int n4)
{
    int idx = blockIdx.x * 256 + threadIdx.x;
    if (idx < 65536) {
        int n = idx >> 8, k = idx & 255;
        WvT[idx] = f2bf(Wv[k * 256 + n]);
    } else if (idx < 163840) {
        int l = idx - 65536; int n = l >> 8, k = l & 255;
        WoaT[l] = f2bf(n < 256 ? Woff[k * 256 + n] : Wattn[k * 128 + (n - 256)]);
    } else if (idx < 229376) {
        int l = idx - 163840; int n = l >> 8, k = l & 255;
        WoutT[l] = f2bf(Wout[k * 256 + n]);
    } else if (idx < 491520) {
        int l = idx - 229376; int n = l >> 8, k = l & 255;
        W1T[l] = f2bf(W1[k * 1024 + n]);
    } else if (idx < 753664) {
        int l = idx - 491520; int n = l >> 10, k = l & 1023;
        W2T[l] = f2bf(W2[k * 256 + n]);
    } else if (idx < 754048) {
        int l = idx - 753664;
        b_oa[l] = (l < 256) ? b_off[l] : b_attn[l - 256];
    } else if (idx < 754048 + n4) {
        int i = idx - 754048;
        float4 v = reinterpret_cast<const float4*>(value)[i];
        us4 r = { f2bf(v.x), f2bf(v.y), f2bf(v.z), f2bf(v.w) };
        reinterpret_cast<us4*>(v16)[i] = r;
    } else if (idx < 754048 + 2 * n4) {
        int j = idx - 754048 - n4;
        float4 va = reinterpret_cast<const float4*>(query)[j];
        float4 vb = reinterpret_cast<const float4*>(qpos)[j];
        us4 r = { f2bf(va.x + vb.x), f2bf(va.y + vb.y), f2bf(va.z + vb.z), f2bf(va.w + vb.w) };
        reinterpret_cast<us4*>(q16)[j] = r;
    }
}

// ---------------------------------------------------------------------------
// Fused vproj + off/attn GEMM dispatch. 128x128 tile, BK=32, K=256, 2-phase.
// XCD-chunked swizzle: 840 blocks = 8 XCDs x (21 row-bands x 5 cols).
// vproj path: LDS-staged epilogue -> coalesced 16B head-major writes.
// ---------------------------------------------------------------------------
__global__ __launch_bounds__(256) void gemm_pre(
    const unsigned short* __restrict__ v16, const unsigned short* __restrict__ q16,
    const unsigned short* __restrict__ WvT, const unsigned short* __restrict__ WoaT,
    const float* __restrict__ b_v, const float* __restrict__ b_oa,
    unsigned short* __restrict__ vph, float* __restrict__ oa)
{
    __shared__ unsigned short SM[2][2][128 * 32];   // As=SM[0], Bs=SM[1]; epilogue: 128x128 bf16 tile

    // swizzle: XCD k <- 21 consecutive row-bands x all 5 cols
    const int i   = (int)blockIdx.y * 5 + (int)blockIdx.x;
    const int xcd = i & 7;
    const int jj  = i >> 3;            // 0..104
    const int by  = xcd * 21 + jj / 5;
    const int bx  = jj % 5;

    const bool is_v = (bx < 2);
    const unsigned short* A  = is_v ? v16 : q16;
    const unsigned short* BT = is_v ? WvT : WoaT;
    const float* bias = is_v ? b_v : b_oa;
    const int n0 = (is_v ? bx : bx - 2) * 128;
    const int K = 256;

    const int tid  = threadIdx.x;
    const int wave = tid >> 6;
    const int lane = tid & 63;
    const int m0 = by * 128;
    const int wr = (wave >> 1) * 64;
    const int wc = (wave & 1) * 64;

    f32x4 acc[4][4] = {};
    const int soff = wave * 1024 + lane * 16;

    auto stage = [&](int buf, int k0) {
        #pragma unroll
        for (int p = 0; p < 2; ++p) {
            const int off  = p * 4096 + soff;
            const int row  = off >> 6;
            const int colb = off & 63;
            int ar = m0 + row; ar = (ar < M_) ? ar : (M_ - 1);
            __builtin_amdgcn_global_load_lds(AS1U(A + (size_t)ar * K + k0 + (colb >> 1)),
                AS3U(&SM[0][buf][(p * 4096 + wave * 1024) >> 1]), 16, 0, 0);
            __builtin_amdgcn_global_load_lds(AS1U(BT + (size_t)(n0 + row) * K + k0 + (colb >> 1)),
                AS3U(&SM[1][buf][(p * 4096 + wave * 1024) >> 1]), 16, 0, 0);
        }
    };

    stage(0, 0);
    __syncthreads();
    int cur = 0;
    for (int t = 0; t < 8; ++t) {
        if (t + 1 < 8) stage(cur ^ 1, (t + 1) * 32);
        const int fr = lane & 15;
        const int kb = (lane >> 4) * 8;
        short8 af[4], bf[4];
        #pragma unroll
        for (int m = 0; m < 4; ++m)
            af[m] = *reinterpret_cast<const short8*>(&SM[0][cur][(wr + m * 16 + fr) * 32 + kb]);
        #pragma unroll
        for (int n = 0; n < 4; ++n)
            bf[n] = *reinterpret_cast<const short8*>(&SM[1][cur][(wc + n * 16 + fr) * 32 + kb]);
        #pragma unroll
        for (int m = 0; m < 4; ++m)
            #pragma unroll
            for (int n = 0; n < 4; ++n)
                acc[m][n] = __builtin_amdgcn_mfma_f32_16x16x32_bf16(af[m], bf[n], acc[m][n], 0, 0, 0);
        if (t + 1 < 8) { __syncthreads(); cur ^= 1; }
    }

    const int fr = lane & 15;
    const int r0 = (lane >> 4) * 4;
    if (is_v) {
        // ---- LDS-staged coalesced epilogue (bf16, head-major) ----
        __syncthreads();
        unsigned short* Ct = &SM[0][0][0];   // 128x128 bf16 = 32 KB
        #pragma unroll
        for (int n = 0; n < 4; ++n) {
            const float bv = bias[n0 + wc + n * 16 + fr];
            #pragma unroll
            for (int m = 0; m < 4; ++m)
                #pragma unroll
                for (int r = 0; r < 4; ++r)
                    Ct[(wr + m * 16 + r0 + r) * 128 + wc + n * 16 + fr] = f2bf(acc[m][n][r] + bv);
        }
        __syncthreads();
        #pragma unroll
        for (int pass = 0; pass < 8; ++pass) {
            const int r  = pass * 16 + (tid >> 4);
            const int c8 = (tid & 15) * 8;          // local bf16 col, 16B chunk
            const int row = m0 + r;
            if (row < M_) {
                const int col = n0 + c8;
                const int bb = (row >= LQ_) ? 1 : 0;
                const int lvv = row - bb * LQ_;
                const int hh = col >> 5, dd = col & 31;
                us8 v = *reinterpret_cast<const us8*>(&Ct[r * 128 + c8]);
                *reinterpret_cast<us8*>(&vph[(((size_t)bb * NH_ + hh) * LQ_ + lvv) * 32 + dd]) = v;
            }
        }
    } else {
        // f32 stores are already 64B-granular (16 lanes x 4B contiguous)
        #pragma unroll
        for (int n = 0; n < 4; ++n) {
            const int col = n0 + wc + n * 16 + fr;
            const float bv = bias[col];
            #pragma unroll
            for (int m = 0; m < 4; ++m) {
                #pragma unroll
                for (int r = 0; r < 4; ++r) {
                    const int row = m0 + wr + m * 16 + r0 + r;
                    if (row < M_) oa[(size_t)row * 384 + col] = acc[m][n][r] + bv;
                }
            }
        }
    }
}

// ---------------------------------------------------------------------------
// FFN1 GEMM: 128x128 tile, BK=32, 2-phase dbuf, XCD-chunked swizzle (NX=8),
// relu + bf16 output via LDS-staged coalesced epilogue.
// ---------------------------------------------------------------------------
__global__ __launch_bounds__(256) void gemm_ffn1(
    const unsigned short* __restrict__ A,
    const unsigned short* __restrict__ BT,
    const float* __restrict__ bias,
    unsigned short* __restrict__ Cout,
    int M, int N, int K)
{
    __shared__ unsigned short SM[2][2][128 * 32];

    // swizzle: 1344 blocks = 8 XCDs x (21 row-bands x 8 cols)
    const int i   = (int)blockIdx.y * 8 + (int)blockIdx.x;
    const int xcd = i & 7;
    const int jj  = i >> 3;            // 0..167
    const int by  = xcd * 21 + (jj >> 3);
    const int bx  = jj & 7;

    const int tid  = threadIdx.x;
    const int wave = tid >> 6;
    const int lane = tid & 63;
    const int m0 = by * 128;
    const int n0 = bx * 128;
    const int wr = (wave >> 1) * 64;
    const int wc = (wave & 1) * 64;

    f32x4 acc[4][4] = {};
    const int soff = wave * 1024 + lane * 16;

    auto stage = [&](int buf, int k0) {
        #pragma unroll
        for (int p = 0; p < 2; ++p) {
            const int off  = p * 4096 + soff;
            const int row  = off >> 6;
            const int colb = off & 63;
            int ar = m0 + row; ar = (ar < M) ? ar : (M - 1);
            __builtin_amdgcn_global_load_lds(AS1U(A + (size_t)ar * K + k0 + (colb >> 1)),
                AS3U(&SM[0][buf][(p * 4096 + wave * 1024) >> 1]), 16, 0, 0);
            __builtin_amdgcn_global_load_lds(AS1U(BT + (size_t)(n0 + row) * K + k0 + (colb >> 1)),
                AS3U(&SM[1][buf][(p * 4096 + wave * 1024) >> 1]), 16, 0, 0);
        }
    };

    const int nt = K >> 5;
    stage(0, 0);
    __syncthreads();
    int cur = 0;
    for (int t = 0; t < nt; ++t) {
        if (t + 1 < nt) stage(cur ^ 1, (t + 1) * 32);
        const int fr = lane & 15;
        const int kb = (lane >> 4) * 8;
        short8 af[4], bf[4];
        #pragma unroll
        for (int m = 0; m < 4; ++m)
            af[m] = *reinterpret_cast<const short8*>(&SM[0][cur][(wr + m * 16 + fr) * 32 + kb]);
        #pragma unroll
        for (int n = 0; n < 4; ++n)
            bf[n] = *reinterpret_cast<const short8*>(&SM[1][cur][(wc + n * 16 + fr) * 32 + kb]);
        #pragma unroll
        for (int m = 0; m < 4; ++m)
            #pragma unroll
            for (int n = 0; n < 4; ++n)
                acc[m][n] = __builtin_amdgcn_mfma_f32_16x16x32_bf16(af[m], bf[n], acc[m][n], 0, 0, 0);
        if (t + 1 < nt) { __syncthreads(); cur ^= 1; }
    }

    // ---- LDS-staged coalesced epilogue (relu + bf16) ----
    const int fr = lane & 15;
    const int r0 = (lane >> 4) * 4;
    __syncthreads();
    unsigned short* Ct = &SM[0][0][0];
    #pragma unroll
    for (int n = 0; n < 4; ++n) {
        const float bv = bias[n0 + wc + n * 16 + fr];
        #pragma unroll
        for (int m = 0; m < 4; ++m)
            #pragma unroll
            for (int r = 0; r < 4; ++r)
                Ct[(wr + m * 16 + r0 + r) * 128 + wc + n * 16 + fr] = f2bf(fmaxf(acc[m][n][r] + bv, 0.f));
    }
    __syncthreads();
    #pragma unroll
    for (int pass = 0; pass < 8; ++pass) {
        const int r  = pass * 16 + (tid >> 4);
        const int c8 = (tid & 15) * 8;
        const int row = m0 + r;
        if (row < M) {
            us8 v = *reinterpret_cast<const us8*>(&Ct[r * 128 + c8]);
            *reinterpret_cast<us8*>(&Cout[(size_t)row * N + n0 + c8]) = v;
        }
    }
}

// ---------------------------------------------------------------------------
// GEMM (N=256) + bias + residual + LayerNorm, fused. 2-phase double-buffered.
// BM=64, BN=256, BK=32, 512 threads = 8 waves (2 row x 4 col).
// ---------------------------------------------------------------------------
template<int MIRROR>
__global__ __launch_bounds__(512) void gemm_ln(
    const unsigned short* __restrict__ A,
    const unsigned short* __restrict__ BT,
    const float* __restrict__ bias,
    const float* __restrict__ res,
    const float* __restrict__ g,
    const float* __restrict__ beta,
    float* __restrict__ outf,
    unsigned short* __restrict__ out16,
    int M, int K)
{
    __shared__ unsigned short As[2][64 * 32];
    __shared__ unsigned short Bs[2][256 * 32];
    __shared__ float2 sRed[4][64];

    const int tid  = threadIdx.x;
    const int wave = tid >> 6;
    const int lane = tid & 63;
    const int m0 = blockIdx.x * 64;
    const int wr = (wave >> 2) * 32;
    const int wc = (wave & 3) * 64;

    f32x4 acc[2][4] = {};

    auto stage = [&](int buf, int k0) {
        if (tid < 256) {
            const int off  = tid * 16;
            const int row  = off >> 6;
            const int colb = off & 63;
            int ar = m0 + row; ar = (ar < M) ? ar : (M - 1);
            __builtin_amdgcn_global_load_lds(AS1U(A + (size_t)ar * K + k0 + (colb >> 1)),
                AS3U(&As[buf][(wave * 1024) >> 1]), 16, 0, 0);
        }
        #pragma unroll
        for (int p = 0; p < 2; ++p) {
            const int off  = p * 8192 + tid * 16;
            const int row  = off >> 6;
            const int colb = off & 63;
            __builtin_amdgcn_global_load_lds(AS1U(BT + (size_t)row * K + k0 + (colb >> 1)),
                AS3U(&Bs[buf][(p * 8192 + wave * 1024) >> 1]), 16, 0, 0);
        }
    };

    const int nt = K >> 5;
    stage(0, 0);
    __syncthreads();
    int cur = 0;
    for (int t = 0; t < nt; ++t) {
        if (t + 1 < nt) stage(cur ^ 1, (t + 1) * 32);
        const int fr = lane & 15;
        const int kb = (lane >> 4) * 8;
        short8 af[2], bf[4];
        #pragma unroll
        for (int m = 0; m < 2; ++m)
            af[m] = *reinterpret_cast<const short8*>(&As[cur][(wr + m * 16 + fr) * 32 + kb]);
        #pragma unroll
        for (int n = 0; n < 4; ++n)
            bf[n] = *reinterpret_cast<const short8*>(&Bs[cur][(wc + n * 16 + fr) * 32 + kb]);
        #pragma unroll
        for (int m = 0; m < 2; ++m)
            #pragma unroll
            for (int n = 0; n < 4; ++n)
                acc[m][n] = __builtin_amdgcn_mfma_f32_16x16x32_bf16(af[m], bf[n], acc[m][n], 0, 0, 0);
        if (t + 1 < nt) { __syncthreads(); cur ^= 1; }
    }

    const int fr = lane & 15;
    const int r0 = (lane >> 4) * 4;
    float biasv[4], gv[4], bev[4];
    #pragma unroll
    for (int n = 0; n < 4; ++n) {
        const int col = wc + n * 16 + fr;
        biasv[n] = bias[col]; gv[n] = g[col]; bev[n] = beta[col];
    }
    #pragma unroll
    for (int m = 0; m < 2; ++m) {
        #pragma unroll
        for (int r = 0; r < 4; ++r) {
            int row = m0 + wr + m * 16 + r0 + r;
            int rr = (row < M) ? row : (M - 1);
            const float* rp = res + (size_t)rr * 256;
            #pragma unroll
            for (int n = 0; n < 4; ++n)
                acc[m][n][r] += biasv[n] + rp[wc + n * 16 + fr];
        }
    }
    #pragma unroll
    for (int m = 0; m < 2; ++m) {
        #pragma unroll
        for (int r = 0; r < 4; ++r) {
            float sx = 0.f, sxx = 0.f;
            #pragma unroll
            for (int n = 0; n < 4; ++n) { float t = acc[m][n][r]; sx += t; sxx += t * t; }
            #pragma unroll
            for (int mask = 1; mask < 16; mask <<= 1) {
                sx  += __shfl_xor(sx, mask);
                sxx += __shfl_xor(sxx, mask);
            }
            if (fr == 0) sRed[wave & 3][wr + m * 16 + r0 + r] = make_float2(sx, sxx);
        }
    }
    __syncthreads();
    #pragma unroll
    for (int m = 0; m < 2; ++m) {
        #pragma unroll
        for (int r = 0; r < 4; ++r) {
            const int lr = wr + m * 16 + r0 + r;
            float2 a0 = sRed[0][lr], a1 = sRed[1][lr], a2 = sRed[2][lr], a3 = sRed[3][lr];
            const float S  = a0.x + a1.x + a2.x + a3.x;
            const float SS = a0.y + a1.y + a2.y + a3.y;
            const float mean = S * (1.f / 256.f);
            const float var  = SS * (1.f / 256.f) - mean * mean;
            const float rstd = rsqrtf(var + 1e-5f);
            const int row = m0 + lr;
            if (row < M) {
                #pragma unroll
                for (int n = 0; n < 4; ++n) {
                    const int col = wc + n * 16 + fr;
                    const float y = (acc[m][n][r] - mean) * rstd * gv[n] + bev[n];
                    outf[(size_t)row * 256 + col] = y;
                    if (MIRROR) out16[(size_t)row * 256 + col] = f2bf(y);
                }
            }
        }
    }
}

// ---------------------------------------------------------------------------
// Multi-scale deformable attention, XCD-local by head (round-9 structure:
// 4 lanes/query x 16B, depth-2 pipelined gathers).
// ---------------------------------------------------------------------------
__global__ __launch_bounds__(256) void msdeform_kernel(
    const unsigned short* __restrict__ vproj_h, const float* __restrict__ offattn,
    const float* __restrict__ refp, unsigned short* __restrict__ msout)
{
    __shared__ int4   sIdx[4][16][17];
    __shared__ float4 sWgt[4][16][17];

    const int bh = blockIdx.x & 15;          // b*8 + h
    const int qc = blockIdx.x >> 4;
    const int b  = bh >> 3;
    const int h  = bh & 7;
    const int wave = threadIdx.x >> 6;
    const int lane = threadIdx.x & 63;
    const int qq = lane >> 2;                // query within wave (0..15)
    const int j  = lane & 3;                 // level (ph1) / channel-octet (ph2)
    const int lv = qc * 64 + wave * 16 + qq;
    if (lv >= LQ_) return;
    const int bq = b * LQ_ + lv;

    // ---- phase 1: level j, points 4j..4j+3 ----
    const float4 oA = *reinterpret_cast<const float4*>(offattn + (size_t)bq * 384 + h * 32 + 8 * j);
    const float4 oB = *reinterpret_cast<const float4*>(offattn + (size_t)bq * 384 + h * 32 + 8 * j + 4);
    const float4 lg = *reinterpret_cast<const float4*>(offattn + (size_t)bq * 384 + 256 + h * 16 + 4 * j);
    const float2 rp = *reinterpret_cast<const float2*>(refp + (size_t)bq * 8 + 2 * j);

    const float Wf[4] = {106.f, 53.f, 27.f, 14.f};
    const float Hf[4] = {76.f, 38.f, 19.f, 10.f};
    const int   Wi[4] = {106, 53, 27, 14};
    const int   Hi[4] = {76, 38, 19, 10};
    const int   St[4] = {0, 8056, 10070, 10583};

    float mx = fmaxf(fmaxf(lg.x, lg.y), fmaxf(lg.z, lg.w));
    mx = fmaxf(mx, __shfl_xor(mx, 1));
    mx = fmaxf(mx, __shfl_xor(mx, 2));
    const float e0 = __expf(lg.x - mx), e1 = __expf(lg.y - mx);
    const float e2 = __expf(lg.z - mx), e3 = __expf(lg.w - mx);
    float s = e0 + e1 + e2 + e3;
    s += __shfl_xor(s, 1); s += __shfl_xor(s, 2);
    const float inv = 1.f / s;

    const int W = Wi[j], H = Hi[j];
    const float Wff = Wf[j], Hff = Hf[j];
    const int base = St[j];
    const float oxs[4] = {oA.x, oA.z, oB.x, oB.z};
    const float oys[4] = {oA.y, oA.w, oB.y, oB.w};
    const float ews[4] = {e0, e1, e2, e3};

    #pragma unroll
    for (int i = 0; i < 4; ++i) {
        const float aw = ews[i] * inv;
        const float x = fmaf(rp.x, Wff, oxs[i]) - 0.5f;
        const float y = fmaf(rp.y, Hff, oys[i]) - 0.5f;
        const float xf = floorf(x), yf = floorf(y);
        const float fx = x - xf, fy = y - yf;
        const int x0 = (int)xf, y0 = (int)yf;
        const float gx = 1.f - fx, gy = 1.f - fy;
        const bool vx0 = (x0 >= 0) && (x0 < W);
        const bool vx1 = (x0 + 1 >= 0) && (x0 + 1 < W);
        const bool vy0 = (y0 >= 0) && (y0 < H);
        const bool vy1 = (y0 + 1 >= 0) && (y0 + 1 < H);
        const int xc0 = min(max(x0, 0), W - 1);
        const int xc1 = min(max(x0 + 1, 0), W - 1);
        const int yr0 = min(max(y0, 0), H - 1) * W;
        const int yr1 = min(max(y0 + 1, 0), H - 1) * W;
        int4 iv; float4 wv;
        iv.x = (base + yr0 + xc0) << 6;  wv.x = (vx0 && vy0) ? gx * gy * aw : 0.f;
        iv.y = (base + yr0 + xc1) << 6;  wv.y = (vx1 && vy0) ? fx * gy * aw : 0.f;
        iv.z = (base + yr1 + xc0) << 6;  wv.z = (vx0 && vy1) ? gx * fy * aw : 0.f;
        iv.w = (base + yr1 + xc1) << 6;  wv.w = (vx1 && vy1) ? fx * fy * aw : 0.f;
        sIdx[wave][qq][4 * j + i] = iv;
        sWgt[wave][qq][4 * j + i] = wv;
    }

    // ---- phase 2: depth-2 pipelined gather, 16 B/lane/corner ----
    const char* vb = (const char*)(vproj_h + (size_t)bh * LQ_ * 32) + j * 16;
    f32x4 accA = {0.f, 0.f, 0.f, 0.f};
    f32x4 accB = {0.f, 0.f, 0.f, 0.f};

    int4 iv0 = sIdx[wave][qq][0];
    u32x4 a0 = *reinterpret_cast<const u32x4*>(vb + (unsigned)iv0.x);
    u32x4 a1 = *reinterpret_cast<const u32x4*>(vb + (unsigned)iv0.y);
    u32x4 a2 = *reinterpret_cast<const u32x4*>(vb + (unsigned)iv0.z);
    u32x4 a3 = *reinterpret_cast<const u32x4*>(vb + (unsigned)iv0.w);

    #pragma unroll
    for (int p = 0; p < 16; ++p) {
        u32x4 b0, b1, b2, b3;
        if (p < 15) {
            const int4 nv = sIdx[wave][qq][p + 1];
            b0 = *reinterpret_cast<const u32x4*>(vb + (unsigned)nv.x);
            b1 = *reinterpret_cast<const u32x4*>(vb + (unsigned)nv.y);
            b2 = *reinterpret_cast<const u32x4*>(vb + (unsigned)nv.z);
            b3 = *reinterpret_cast<const u32x4*>(vb + (unsigned)nv.w);
        }
        const float4 wv = sWgt[wave][qq][p];
        accA[0] = fmaf(wv.x, bflo(a0.x), accA[0]); accA[1] = fmaf(wv.x, bfhi(a0.x), accA[1]);
        accA[2] = fmaf(wv.x, bflo(a0.y), accA[2]); accA[3] = fmaf(wv.x, bfhi(a0.y), accA[3]);
        accB[0] = fmaf(wv.x, bflo(a0.z), accB[0]); accB[1] = fmaf(wv.x, bfhi(a0.z), accB[1]);
        accB[2] = fmaf(wv.x, bflo(a0.w), accB[2]); accB[3] = fmaf(wv.x, bfhi(a0.w), accB[3]);
        accA[0] = fmaf(wv.y, bflo(a1.x), accA[0]); accA[1] = fmaf(wv.y, bfhi(a1.x), accA[1]);
        accA[2] = fmaf(wv.y, bflo(a1.y), accA[2]); accA[3] = fmaf(wv.y, bfhi(a1.y), accA[3]);
        accB[0] = fmaf(wv.y, bflo(a1.z), accB[0]); accB[1] = fmaf(wv.y, bfhi(a1.z), accB[1]);
        accB[2] = fmaf(wv.y, bflo(a1.w), accB[2]); accB[3] = fmaf(wv.y, bfhi(a1.w), accB[3]);
        accA[0] = fmaf(wv.z, bflo(a2.x), accA[0]); accA[1] = fmaf(wv.z, bfhi(a2.x), accA[1]);
        accA[2] = fmaf(wv.z, bflo(a2.y), accA[2]); accA[3] = fmaf(wv.z, bfhi(a2.y), accA[3]);
        accB[0] = fmaf(wv.z, bflo(a2.z), accB[0]); accB[1] = fmaf(wv.z, bfhi(a2.z), accB[1]);
        accB[2] = fmaf(wv.z, bflo(a2.w), accB[2]); accB[3] = fmaf(wv.z, bfhi(a2.w), accB[3]);
        accA[0] = fmaf(wv.w, bflo(a3.x), accA[0]); accA[1] = fmaf(wv.w, bfhi(a3.x), accA[1]);
        accA[2] = fmaf(wv.w, bflo(a3.y), accA[2]); accA[3] = fmaf(wv.w, bfhi(a3.y), accA[3]);
        accB[0] = fmaf(wv.w, bflo(a3.z), accB[0]); accB[1] = fmaf(wv.w, bfhi(a3.z), accB[1]);
        accB[2] = fmaf(wv.w, bflo(a3.w), accB[2]); accB[3] = fmaf(wv.w, bfhi(a3.w), accB[3]);
        a0 = b0; a1 = b1; a2 = b2; a3 = b3;
    }
    us8 r = { f2bf(accA[0]), f2bf(accA[1]), f2bf(accA[2]), f2bf(accA[3]),
              f2bf(accB[0]), f2bf(accB[1]), f2bf(accB[2]), f2bf(accB[3]) };
    *reinterpret_cast<us8*>(msout + (size_t)bq * 256 + h * 32 + j * 8) = r;
}

// ---------------------------------------------------------------------------
extern "C" void kernel_launch(void* const* d_in, const int* in_sizes, int n_in,
                              void* d_out, int out_size, void* d_ws, size_t ws_size,
                              hipStream_t stream) {
    const float* query = (const float*)d_in[0];
    const float* qpos  = (const float*)d_in[1];
    const float* value = (const float*)d_in[2];
    const float* refp  = (const float*)d_in[3];
    const float* W_off  = (const float*)d_in[6];
    const float* b_off  = (const float*)d_in[7];
    const float* W_attn = (const float*)d_in[8];
    const float* b_attn = (const float*)d_in[9];
    const float* W_v    = (const float*)d_in[10];
    const float* b_v    = (const float*)d_in[11];
    const float* W_out  = (const float*)d_in[12];
    const float* b_out  = (const float*)d_in[13];
    const float* ln1_g  = (const float*)d_in[14];
    const float* ln1_b  = (const float*)d_in[15];
    const float* W1     = (const float*)d_in[16];
    const float* b1     = (const float*)d_in[17];
    const float* W2     = (const float*)d_in[18];
    const float* b2     = (const float*)d_in[19];
    const float* ln2_g  = (const float*)d_in[20];
    const float* ln2_b  = (const float*)d_in[21];
    float* out = (float*)d_out;

    // ---- workspace layout ----
    unsigned short* WvT   = (unsigned short*)d_ws;
    unsigned short* WoaT  = WvT   + 65536;    // 384 x 256  (off | attn)
    unsigned short* WoutT = WoaT  + 98304;
    unsigned short* W1T   = WoutT + 65536;    // 1024 x 256
    unsigned short* W2T   = W1T   + 262144;   // 256 x 1024
    float* b_oa = (float*)(W2T + 262144);     // 384 f32
    uint8_t* base = (uint8_t*)(b_oa + 384);
    base = (uint8_t*)(((uintptr_t)base + 255) & ~(uintptr_t)255);

    const size_t A = (size_t)M_ * D_;
    unsigned short* R_v16  = (unsigned short*)base;          // value bf16 -> q1 bf16 mirror
    unsigned short* R_q16  = R_v16 + A;                      // q bf16 -> ms16
    unsigned short* R_vph  = R_q16 + A;                      // vproj bf16 head-major
    float* R_oa  = (float*)(R_vph + A);                      // off|attn (M,384)
    float* R_q1  = R_oa + (size_t)M_ * 384;                  // q1 f32
    unsigned short* R_h16 = (unsigned short*)(R_q1 + A);     // FFN hidden bf16 (M,1024)

    const dim3 blk(256);
    auto cdiv = [](size_t a, size_t b) { return (unsigned)((a + b - 1) / b); };

    const int n4 = (int)(A / 4);
    prep_kernel<<<cdiv(754048 + 2 * (size_t)n4, 256), blk, 0, stream>>>(
        W_v, W_off, W_attn, W_out, W1, W2, b_off, b_attn, value, query, qpos,
        WvT, WoaT, WoutT, W1T, W2T, b_oa, R_v16, R_q16, n4);

    const unsigned MT = (M_ + 127) / 128;   // 168
    // vproj (head-major bf16, coalesced) + off|attn (f32), one swizzled dispatch
    gemm_pre<<<dim3(5, MT), blk, 0, stream>>>(
        R_v16, R_q16, WvT, WoaT, b_v, b_oa, R_vph, R_oa);
    // deformable attention -> ms16 (overwrites R_q16, dead)
    const unsigned nQC = cdiv(LQ_, 64);   // 168
    msdeform_kernel<<<dim3(nQC * 16), blk, 0, stream>>>(R_vph, R_oa, refp, R_q16);
    // q1 = LN(query + ms16@WoutT^T + b_out): f32 -> R_q1, bf16 -> R_v16 (dead)
    gemm_ln<1><<<dim3(cdiv(M_, 64)), dim3(512), 0, stream>>>(
        R_q16, WoutT, b_out, query, ln1_g, ln1_b, R_q1, R_v16, M_, 256);
    // h = relu(q1b @ W1T^T) bf16, swizzled + coalesced epilogue
    gemm_ffn1<<<dim3(8, MT), blk, 0, stream>>>(R_v16, W1T, b1, R_h16, M_, 1024, 256);
    // out = LN(q1 + h@W2T^T + b2)
    gemm_ln<0><<<dim3(cdiv(M_, 64)), dim3(512), 0, stream>>>(
        R_h16, W2T, b2, R_q1, ln2_g, ln2_b, out, nullptr, M_, 1024);
}

// Round 11
// 143.120 us; speedup vs baseline: 1.7374x; 1.0121x over previous
//
#include <hip/hip_runtime.h>
#include <math.h>

#define B_   2
#define LQ_  10723
#define D_   256
#define NH_  8
#define HD_  32
#define NL_  4
#define NP_  4
#define DFF_ 1024
#define M_   (B_ * LQ_)   // 21446

typedef __attribute__((ext_vector_type(4))) float f32x4;
typedef __attribute__((ext_vector_type(8))) short short8;
typedef __attribute__((ext_vector_type(4))) unsigned short us4;
typedef __attribute__((ext_vector_type(8))) unsigned short us8;
typedef __attribute__((ext_vector_type(4))) unsigned int u32x4;

__device__ __forceinline__ unsigned short f2bf(float f) {
    union { float f; unsigned int u; } x; x.f = f;
    unsigned int r = x.u + 0x7FFF + ((x.u >> 16) & 1);   // RNE
    return (unsigned short)(r >> 16);
}
__device__ __forceinline__ float bf2f(unsigned short u) {
    union { unsigned int u; float f; } x; x.u = (unsigned int)u << 16;
    return x.f;
}
__device__ __forceinline__ float bflo(unsigned int u) {
    union { unsigned int u; float f; } x; x.u = u << 16; return x.f;
}
__device__ __forceinline__ float bfhi(unsigned int u) {
    union { unsigned int u; float f; } x; x.u = u & 0xffff0000u; return x.f;
}

#define AS3U(p) ((__attribute__((address_space(3))) unsigned int*)(uintptr_t)(p))
#define AS1U(p) ((const __attribute__((address_space(1))) unsigned int*)(uintptr_t)(p))

// ---------------------------------------------------------------------------
// Fused prep: weight transpose/convert + bias concat + activation convert.
// ---------------------------------------------------------------------------
__global__ __launch_bounds__(256) void prep_kernel(
    const float* __restrict__ Wv, const float* __restrict__ Woff,
    const float* __restrict__ Wattn, const float* __restrict__ Wout,
    const float* __restrict__ W1, const float* __restrict__ W2,
    const float* __restrict__ b_off, const float* __restrict__ b_attn,
    const float* __restrict__ value, const float* __restrict__ query,
    const float* __restrict__ qpos,
    unsigned short* __restrict__ WvT, unsigned short* __restrict__ WoaT,
    unsigned short* __restrict__ WoutT, unsigned short* __restrict__ W1T,
    unsigned short* __restrict__ W2T, float* __restrict__ b_oa,
    unsigned short* __restrict__ v16, unsigned short* __restrict__ q16, int n4)
{
    int idx = blockIdx.x * 256 + threadIdx.x;
    if (idx < 65536) {
        int n = idx >> 8, k = idx & 255;
        WvT[idx] = f2bf(Wv[k * 256 + n]);
    } else if (idx < 163840) {
        int l = idx - 65536; int n = l >> 8, k = l & 255;
        WoaT[l] = f2bf(n < 256 ? Woff[k * 256 + n] : Wattn[k * 128 + (n - 256)]);
    } else if (idx < 229376) {
        int l = idx - 163840; int n = l >> 8, k = l & 255;
        WoutT[l] = f2bf(Wout[k * 256 + n]);
    } else if (idx < 491520) {
        int l = idx - 229376; int n = l >> 8, k = l & 255;
        W1T[l] = f2bf(W1[k * 1024 + n]);
    } else if (idx < 753664) {
        int l = idx - 491520; int n = l >> 10, k = l & 1023;
        W2T[l] = f2bf(W2[k * 256 + n]);
    } else if (idx < 754048) {
        int l = idx - 753664;
        b_oa[l] = (l < 256) ? b_off[l] : b_attn[l - 256];
    } else if (idx < 754048 + n4) {
        int i = idx - 754048;
        float4 v = reinterpret_cast<const float4*>(value)[i];
        us4 r = { f2bf(v.x), f2bf(v.y), f2bf(v.z), f2bf(v.w) };
        reinterpret_cast<us4*>(v16)[i] = r;
    } else if (idx < 754048 + 2 * n4) {
        int j = idx - 754048 - n4;
        float4 va = reinterpret_cast<const float4*>(query)[j];
        float4 vb = reinterpret_cast<const float4*>(qpos)[j];
        us4 r = { f2bf(va.x + vb.x), f2bf(va.y + vb.y), f2bf(va.z + vb.z), f2bf(va.w + vb.w) };
        reinterpret_cast<us4*>(q16)[j] = r;
    }
}

// ---------------------------------------------------------------------------
// Fused vproj + off/attn GEMM dispatch. 128x128 tile, BK=32, K=256, 2-phase.
// XCD-chunked swizzle: 840 blocks = 8 XCDs x (21 row-bands x 5 cols).
// vproj path: LDS-staged epilogue -> coalesced 16B head-major writes.
// ---------------------------------------------------------------------------
__global__ __launch_bounds__(256) void gemm_pre(
    const unsigned short* __restrict__ v16, const unsigned short* __restrict__ q16,
    const unsigned short* __restrict__ WvT, const unsigned short* __restrict__ WoaT,
    const float* __restrict__ b_v, const float* __restrict__ b_oa,
    unsigned short* __restrict__ vph, float* __restrict__ oa)
{
    __shared__ unsigned short SM[2][2][128 * 32];   // As=SM[0], Bs=SM[1]; epilogue: 128x128 bf16 tile

    // swizzle: XCD k <- 21 consecutive row-bands x all 5 cols
    const int i   = (int)blockIdx.y * 5 + (int)blockIdx.x;
    const int xcd = i & 7;
    const int jj  = i >> 3;            // 0..104
    const int by  = xcd * 21 + jj / 5;
    const int bx  = jj % 5;

    const bool is_v = (bx < 2);
    const unsigned short* A  = is_v ? v16 : q16;
    const unsigned short* BT = is_v ? WvT : WoaT;
    const float* bias = is_v ? b_v : b_oa;
    const int n0 = (is_v ? bx : bx - 2) * 128;
    const int K = 256;

    const int tid  = threadIdx.x;
    const int wave = tid >> 6;
    const int lane = tid & 63;
    const int m0 = by * 128;
    const int wr = (wave >> 1) * 64;
    const int wc = (wave & 1) * 64;

    f32x4 acc[4][4] = {};
    const int soff = wave * 1024 + lane * 16;

    auto stage = [&](int buf, int k0) {
        #pragma unroll
        for (int p = 0; p < 2; ++p) {
            const int off  = p * 4096 + soff;
            const int row  = off >> 6;
            const int colb = off & 63;
            int ar = m0 + row; ar = (ar < M_) ? ar : (M_ - 1);
            __builtin_amdgcn_global_load_lds(AS1U(A + (size_t)ar * K + k0 + (colb >> 1)),
                AS3U(&SM[0][buf][(p * 4096 + wave * 1024) >> 1]), 16, 0, 0);
            __builtin_amdgcn_global_load_lds(AS1U(BT + (size_t)(n0 + row) * K + k0 + (colb >> 1)),
                AS3U(&SM[1][buf][(p * 4096 + wave * 1024) >> 1]), 16, 0, 0);
        }
    };

    stage(0, 0);
    __syncthreads();
    int cur = 0;
    for (int t = 0; t < 8; ++t) {
        if (t + 1 < 8) stage(cur ^ 1, (t + 1) * 32);
        const int fr = lane & 15;
        const int kb = (lane >> 4) * 8;
        short8 af[4], bf[4];
        #pragma unroll
        for (int m = 0; m < 4; ++m)
            af[m] = *reinterpret_cast<const short8*>(&SM[0][cur][(wr + m * 16 + fr) * 32 + kb]);
        #pragma unroll
        for (int n = 0; n < 4; ++n)
            bf[n] = *reinterpret_cast<const short8*>(&SM[1][cur][(wc + n * 16 + fr) * 32 + kb]);
        #pragma unroll
        for (int m = 0; m < 4; ++m)
            #pragma unroll
            for (int n = 0; n < 4; ++n)
                acc[m][n] = __builtin_amdgcn_mfma_f32_16x16x32_bf16(af[m], bf[n], acc[m][n], 0, 0, 0);
        if (t + 1 < 8) { __syncthreads(); cur ^= 1; }
    }

    const int fr = lane & 15;
    const int r0 = (lane >> 4) * 4;
    if (is_v) {
        // ---- LDS-staged coalesced epilogue (bf16, head-major) ----
        __syncthreads();
        unsigned short* Ct = &SM[0][0][0];   // 128x128 bf16 = 32 KB
        #pragma unroll
        for (int n = 0; n < 4; ++n) {
            const float bv = bias[n0 + wc + n * 16 + fr];
            #pragma unroll
            for (int m = 0; m < 4; ++m)
                #pragma unroll
                for (int r = 0; r < 4; ++r)
                    Ct[(wr + m * 16 + r0 + r) * 128 + wc + n * 16 + fr] = f2bf(acc[m][n][r] + bv);
        }
        __syncthreads();
        #pragma unroll
        for (int pass = 0; pass < 8; ++pass) {
            const int r  = pass * 16 + (tid >> 4);
            const int c8 = (tid & 15) * 8;          // local bf16 col, 16B chunk
            const int row = m0 + r;
            if (row < M_) {
                const int col = n0 + c8;
                const int bb = (row >= LQ_) ? 1 : 0;
                const int lvv = row - bb * LQ_;
                const int hh = col >> 5, dd = col & 31;
                us8 v = *reinterpret_cast<const us8*>(&Ct[r * 128 + c8]);
                *reinterpret_cast<us8*>(&vph[(((size_t)bb * NH_ + hh) * LQ_ + lvv) * 32 + dd]) = v;
            }
        }
    } else {
        // f32 stores are already 64B-granular (16 lanes x 4B contiguous)
        #pragma unroll
        for (int n = 0; n < 4; ++n) {
            const int col = n0 + wc + n * 16 + fr;
            const float bv = bias[col];
            #pragma unroll
            for (int m = 0; m < 4; ++m) {
                #pragma unroll
                for (int r = 0; r < 4; ++r) {
                    const int row = m0 + wr + m * 16 + r0 + r;
                    if (row < M_) oa[(size_t)row * 384 + col] = acc[m][n][r] + bv;
                }
            }
        }
    }
}

// ---------------------------------------------------------------------------
// FFN1 GEMM: 128x128 tile, BK=32, 2-phase dbuf, XCD-chunked swizzle (NX=8),
// relu + bf16 output via LDS-staged coalesced epilogue.
// ---------------------------------------------------------------------------
__global__ __launch_bounds__(256) void gemm_ffn1(
    const unsigned short* __restrict__ A,
    const unsigned short* __restrict__ BT,
    const float* __restrict__ bias,
    unsigned short* __restrict__ Cout,
    int M, int N, int K)
{
    __shared__ unsigned short SM[2][2][128 * 32];

    // swizzle: 1344 blocks = 8 XCDs x (21 row-bands x 8 cols)
    const int i   = (int)blockIdx.y * 8 + (int)blockIdx.x;
    const int xcd = i & 7;
    const int jj  = i >> 3;            // 0..167
    const int by  = xcd * 21 + (jj >> 3);
    const int bx  = jj & 7;

    const int tid  = threadIdx.x;
    const int wave = tid >> 6;
    const int lane = tid & 63;
    const int m0 = by * 128;
    const int n0 = bx * 128;
    const int wr = (wave >> 1) * 64;
    const int wc = (wave & 1) * 64;

    f32x4 acc[4][4] = {};
    const int soff = wave * 1024 + lane * 16;

    auto stage = [&](int buf, int k0) {
        #pragma unroll
        for (int p = 0; p < 2; ++p) {
            const int off  = p * 4096 + soff;
            const int row  = off >> 6;
            const int colb = off & 63;
            int ar = m0 + row; ar = (ar < M) ? ar : (M - 1);
            __builtin_amdgcn_global_load_lds(AS1U(A + (size_t)ar * K + k0 + (colb >> 1)),
                AS3U(&SM[0][buf][(p * 4096 + wave * 1024) >> 1]), 16, 0, 0);
            __builtin_amdgcn_global_load_lds(AS1U(BT + (size_t)(n0 + row) * K + k0 + (colb >> 1)),
                AS3U(&SM[1][buf][(p * 4096 + wave * 1024) >> 1]), 16, 0, 0);
        }
    };

    const int nt = K >> 5;
    stage(0, 0);
    __syncthreads();
    int cur = 0;
    for (int t = 0; t < nt; ++t) {
        if (t + 1 < nt) stage(cur ^ 1, (t + 1) * 32);
        const int fr = lane & 15;
        const int kb = (lane >> 4) * 8;
        short8 af[4], bf[4];
        #pragma unroll
        for (int m = 0; m < 4; ++m)
            af[m] = *reinterpret_cast<const short8*>(&SM[0][cur][(wr + m * 16 + fr) * 32 + kb]);
        #pragma unroll
        for (int n = 0; n < 4; ++n)
            bf[n] = *reinterpret_cast<const short8*>(&SM[1][cur][(wc + n * 16 + fr) * 32 + kb]);
        #pragma unroll
        for (int m = 0; m < 4; ++m)
            #pragma unroll
            for (int n = 0; n < 4; ++n)
                acc[m][n] = __builtin_amdgcn_mfma_f32_16x16x32_bf16(af[m], bf[n], acc[m][n], 0, 0, 0);
        if (t + 1 < nt) { __syncthreads(); cur ^= 1; }
    }

    // ---- LDS-staged coalesced epilogue (relu + bf16) ----
    const int fr = lane & 15;
    const int r0 = (lane >> 4) * 4;
    __syncthreads();
    unsigned short* Ct = &SM[0][0][0];
    #pragma unroll
    for (int n = 0; n < 4; ++n) {
        const float bv = bias[n0 + wc + n * 16 + fr];
        #pragma unroll
        for (int m = 0; m < 4; ++m)
            #pragma unroll
            for (int r = 0; r < 4; ++r)
                Ct[(wr + m * 16 + r0 + r) * 128 + wc + n * 16 + fr] = f2bf(fmaxf(acc[m][n][r] + bv, 0.f));
    }
    __syncthreads();
    #pragma unroll
    for (int pass = 0; pass < 8; ++pass) {
        const int r  = pass * 16 + (tid >> 4);
        const int c8 = (tid & 15) * 8;
        const int row = m0 + r;
        if (row < M) {
            us8 v = *reinterpret_cast<const us8*>(&Ct[r * 128 + c8]);
            *reinterpret_cast<us8*>(&Cout[(size_t)row * N + n0 + c8]) = v;
        }
    }
}

// ---------------------------------------------------------------------------
// GEMM (N=256) + bias + residual + LayerNorm, fused. 2-phase double-buffered.
// BM=64, BN=256, BK=32, 512 threads = 8 waves (2 row x 4 col).
// RES_BF16: residual source dtype (0 = f32, 1 = bf16).
// OUT_F32:  1 = direct f32 stores (final output); 0 = bf16 via LDS-coalesced
//           epilogue (q1b for FFN1 + LN2 residual).
// ---------------------------------------------------------------------------
template<int RES_BF16, int OUT_F32>
__global__ __launch_bounds__(512) void gemm_ln(
    const unsigned short* __restrict__ A,
    const unsigned short* __restrict__ BT,
    const float* __restrict__ bias,
    const void* __restrict__ resp,
    const float* __restrict__ g,
    const float* __restrict__ beta,
    void* __restrict__ outp,
    int M, int K)
{
    __shared__ unsigned short As[2][64 * 32];
    __shared__ unsigned short Bs[2][256 * 32];   // doubles as 64x256 bf16 out tile
    __shared__ float2 sRed[4][64];

    const int tid  = threadIdx.x;
    const int wave = tid >> 6;
    const int lane = tid & 63;
    const int m0 = blockIdx.x * 64;
    const int wr = (wave >> 2) * 32;
    const int wc = (wave & 3) * 64;

    f32x4 acc[2][4] = {};

    auto stage = [&](int buf, int k0) {
        if (tid < 256) {
            const int off  = tid * 16;
            const int row  = off >> 6;
            const int colb = off & 63;
            int ar = m0 + row; ar = (ar < M) ? ar : (M - 1);
            __builtin_amdgcn_global_load_lds(AS1U(A + (size_t)ar * K + k0 + (colb >> 1)),
                AS3U(&As[buf][(wave * 1024) >> 1]), 16, 0, 0);
        }
        #pragma unroll
        for (int p = 0; p < 2; ++p) {
            const int off  = p * 8192 + tid * 16;
            const int row  = off >> 6;
            const int colb = off & 63;
            __builtin_amdgcn_global_load_lds(AS1U(BT + (size_t)row * K + k0 + (colb >> 1)),
                AS3U(&Bs[buf][(p * 8192 + wave * 1024) >> 1]), 16, 0, 0);
        }
    };

    const int nt = K >> 5;
    stage(0, 0);
    __syncthreads();
    int cur = 0;
    for (int t = 0; t < nt; ++t) {
        if (t + 1 < nt) stage(cur ^ 1, (t + 1) * 32);
        const int fr = lane & 15;
        const int kb = (lane >> 4) * 8;
        short8 af[2], bf[4];
        #pragma unroll
        for (int m = 0; m < 2; ++m)
            af[m] = *reinterpret_cast<const short8*>(&As[cur][(wr + m * 16 + fr) * 32 + kb]);
        #pragma unroll
        for (int n = 0; n < 4; ++n)
            bf[n] = *reinterpret_cast<const short8*>(&Bs[cur][(wc + n * 16 + fr) * 32 + kb]);
        #pragma unroll
        for (int m = 0; m < 2; ++m)
            #pragma unroll
            for (int n = 0; n < 4; ++n)
                acc[m][n] = __builtin_amdgcn_mfma_f32_16x16x32_bf16(af[m], bf[n], acc[m][n], 0, 0, 0);
        if (t + 1 < nt) { __syncthreads(); cur ^= 1; }
    }

    const int fr = lane & 15;
    const int r0 = (lane >> 4) * 4;
    float biasv[4], gv[4], bev[4];
    #pragma unroll
    for (int n = 0; n < 4; ++n) {
        const int col = wc + n * 16 + fr;
        biasv[n] = bias[col]; gv[n] = g[col]; bev[n] = beta[col];
    }
    // bias + residual
    #pragma unroll
    for (int m = 0; m < 2; ++m) {
        #pragma unroll
        for (int r = 0; r < 4; ++r) {
            int row = m0 + wr + m * 16 + r0 + r;
            int rr = (row < M) ? row : (M - 1);
            if (RES_BF16) {
                const unsigned short* rp = (const unsigned short*)resp + (size_t)rr * 256;
                #pragma unroll
                for (int n = 0; n < 4; ++n)
                    acc[m][n][r] += biasv[n] + bf2f(rp[wc + n * 16 + fr]);
            } else {
                const float* rp = (const float*)resp + (size_t)rr * 256;
                #pragma unroll
                for (int n = 0; n < 4; ++n)
                    acc[m][n][r] += biasv[n] + rp[wc + n * 16 + fr];
            }
        }
    }
    // per-row {sum, sumsq}
    #pragma unroll
    for (int m = 0; m < 2; ++m) {
        #pragma unroll
        for (int r = 0; r < 4; ++r) {
            float sx = 0.f, sxx = 0.f;
            #pragma unroll
            for (int n = 0; n < 4; ++n) { float t = acc[m][n][r]; sx += t; sxx += t * t; }
            #pragma unroll
            for (int mask = 1; mask < 16; mask <<= 1) {
                sx  += __shfl_xor(sx, mask);
                sxx += __shfl_xor(sxx, mask);
            }
            if (fr == 0) sRed[wave & 3][wr + m * 16 + r0 + r] = make_float2(sx, sxx);
        }
    }
    __syncthreads();   // also: all MFMAs done -> Bs reusable below
    unsigned short* Ct = &Bs[0][0];   // 64x256 bf16 = 32 KB
    #pragma unroll
    for (int m = 0; m < 2; ++m) {
        #pragma unroll
        for (int r = 0; r < 4; ++r) {
            const int lr = wr + m * 16 + r0 + r;
            float2 a0 = sRed[0][lr], a1 = sRed[1][lr], a2 = sRed[2][lr], a3 = sRed[3][lr];
            const float S  = a0.x + a1.x + a2.x + a3.x;
            const float SS = a0.y + a1.y + a2.y + a3.y;
            const float mean = S * (1.f / 256.f);
            const float var  = SS * (1.f / 256.f) - mean * mean;
            const float rstd = rsqrtf(var + 1e-5f);
            const int row = m0 + lr;
            #pragma unroll
            for (int n = 0; n < 4; ++n) {
                const int col = wc + n * 16 + fr;
                const float y = (acc[m][n][r] - mean) * rstd * gv[n] + bev[n];
                if (OUT_F32) {
                    if (row < M) ((float*)outp)[(size_t)row * 256 + col] = y;
                } else {
                    Ct[lr * 256 + col] = f2bf(y);
                }
            }
        }
    }
    if (!OUT_F32) {
        __syncthreads();
        unsigned short* o16 = (unsigned short*)outp;
        #pragma unroll
        for (int pass = 0; pass < 4; ++pass) {
            const int rrow = pass * 16 + (tid >> 5);
            const int cb = (tid & 31) * 8;
            const int grow = m0 + rrow;
            if (grow < M) {
                us8 v = *reinterpret_cast<const us8*>(&Ct[rrow * 256 + cb]);
                *reinterpret_cast<us8*>(&o16[(size_t)grow * 256 + cb]) = v;
            }
        }
    }
}

// ---------------------------------------------------------------------------
// Multi-scale deformable attention, XCD-local by head (round-9 structure:
// 4 lanes/query x 16B, depth-2 pipelined gathers).
// ---------------------------------------------------------------------------
__global__ __launch_bounds__(256) void msdeform_kernel(
    const unsigned short* __restrict__ vproj_h, const float* __restrict__ offattn,
    const float* __restrict__ refp, unsigned short* __restrict__ msout)
{
    __shared__ int4   sIdx[4][16][17];
    __shared__ float4 sWgt[4][16][17];

    const int bh = blockIdx.x & 15;          // b*8 + h
    const int qc = blockIdx.x >> 4;
    const int b  = bh >> 3;
    const int h  = bh & 7;
    const int wave = threadIdx.x >> 6;
    const int lane = threadIdx.x & 63;
    const int qq = lane >> 2;                // query within wave (0..15)
    const int j  = lane & 3;                 // level (ph1) / channel-octet (ph2)
    const int lv = qc * 64 + wave * 16 + qq;
    if (lv >= LQ_) return;
    const int bq = b * LQ_ + lv;

    // ---- phase 1: level j, points 4j..4j+3 ----
    const float4 oA = *reinterpret_cast<const float4*>(offattn + (size_t)bq * 384 + h * 32 + 8 * j);
    const float4 oB = *reinterpret_cast<const float4*>(offattn + (size_t)bq * 384 + h * 32 + 8 * j + 4);
    const float4 lg = *reinterpret_cast<const float4*>(offattn + (size_t)bq * 384 + 256 + h * 16 + 4 * j);
    const float2 rp = *reinterpret_cast<const float2*>(refp + (size_t)bq * 8 + 2 * j);

    const float Wf[4] = {106.f, 53.f, 27.f, 14.f};
    const float Hf[4] = {76.f, 38.f, 19.f, 10.f};
    const int   Wi[4] = {106, 53, 27, 14};
    const int   Hi[4] = {76, 38, 19, 10};
    const int   St[4] = {0, 8056, 10070, 10583};

    float mx = fmaxf(fmaxf(lg.x, lg.y), fmaxf(lg.z, lg.w));
    mx = fmaxf(mx, __shfl_xor(mx, 1));
    mx = fmaxf(mx, __shfl_xor(mx, 2));
    const float e0 = __expf(lg.x - mx), e1 = __expf(lg.y - mx);
    const float e2 = __expf(lg.z - mx), e3 = __expf(lg.w - mx);
    float s = e0 + e1 + e2 + e3;
    s += __shfl_xor(s, 1); s += __shfl_xor(s, 2);
    const float inv = 1.f / s;

    const int W = Wi[j], H = Hi[j];
    const float Wff = Wf[j], Hff = Hf[j];
    const int base = St[j];
    const float oxs[4] = {oA.x, oA.z, oB.x, oB.z};
    const float oys[4] = {oA.y, oA.w, oB.y, oB.w};
    const float ews[4] = {e0, e1, e2, e3};

    #pragma unroll
    for (int i = 0; i < 4; ++i) {
        const float aw = ews[i] * inv;
        const float x = fmaf(rp.x, Wff, oxs[i]) - 0.5f;
        const float y = fmaf(rp.y, Hff, oys[i]) - 0.5f;
        const float xf = floorf(x), yf = floorf(y);
        const float fx = x - xf, fy = y - yf;
        const int x0 = (int)xf, y0 = (int)yf;
        const float gx = 1.f - fx, gy = 1.f - fy;
        const bool vx0 = (x0 >= 0) && (x0 < W);
        const bool vx1 = (x0 + 1 >= 0) && (x0 + 1 < W);
        const bool vy0 = (y0 >= 0) && (y0 < H);
        const bool vy1 = (y0 + 1 >= 0) && (y0 + 1 < H);
        const int xc0 = min(max(x0, 0), W - 1);
        const int xc1 = min(max(x0 + 1, 0), W - 1);
        const int yr0 = min(max(y0, 0), H - 1) * W;
        const int yr1 = min(max(y0 + 1, 0), H - 1) * W;
        int4 iv; float4 wv;
        iv.x = (base + yr0 + xc0) << 6;  wv.x = (vx0 && vy0) ? gx * gy * aw : 0.f;
        iv.y = (base + yr0 + xc1) << 6;  wv.y = (vx1 && vy0) ? fx * gy * aw : 0.f;
        iv.z = (base + yr1 + xc0) << 6;  wv.z = (vx0 && vy1) ? gx * fy * aw : 0.f;
        iv.w = (base + yr1 + xc1) << 6;  wv.w = (vx1 && vy1) ? fx * fy * aw : 0.f;
        sIdx[wave][qq][4 * j + i] = iv;
        sWgt[wave][qq][4 * j + i] = wv;
    }

    // ---- phase 2: depth-2 pipelined gather, 16 B/lane/corner ----
    const char* vb = (const char*)(vproj_h + (size_t)bh * LQ_ * 32) + j * 16;
    f32x4 accA = {0.f, 0.f, 0.f, 0.f};
    f32x4 accB = {0.f, 0.f, 0.f, 0.f};

    int4 iv0 = sIdx[wave][qq][0];
    u32x4 a0 = *reinterpret_cast<const u32x4*>(vb + (unsigned)iv0.x);
    u32x4 a1 = *reinterpret_cast<const u32x4*>(vb + (unsigned)iv0.y);
    u32x4 a2 = *reinterpret_cast<const u32x4*>(vb + (unsigned)iv0.z);
    u32x4 a3 = *reinterpret_cast<const u32x4*>(vb + (unsigned)iv0.w);

    #pragma unroll
    for (int p = 0; p < 16; ++p) {
        u32x4 b0, b1, b2, b3;
        if (p < 15) {
            const int4 nv = sIdx[wave][qq][p + 1];
            b0 = *reinterpret_cast<const u32x4*>(vb + (unsigned)nv.x);
            b1 = *reinterpret_cast<const u32x4*>(vb + (unsigned)nv.y);
            b2 = *reinterpret_cast<const u32x4*>(vb + (unsigned)nv.z);
            b3 = *reinterpret_cast<const u32x4*>(vb + (unsigned)nv.w);
        }
        const float4 wv = sWgt[wave][qq][p];
        accA[0] = fmaf(wv.x, bflo(a0.x), accA[0]); accA[1] = fmaf(wv.x, bfhi(a0.x), accA[1]);
        accA[2] = fmaf(wv.x, bflo(a0.y), accA[2]); accA[3] = fmaf(wv.x, bfhi(a0.y), accA[3]);
        accB[0] = fmaf(wv.x, bflo(a0.z), accB[0]); accB[1] = fmaf(wv.x, bfhi(a0.z), accB[1]);
        accB[2] = fmaf(wv.x, bflo(a0.w), accB[2]); accB[3] = fmaf(wv.x, bfhi(a0.w), accB[3]);
        accA[0] = fmaf(wv.y, bflo(a1.x), accA[0]); accA[1] = fmaf(wv.y, bfhi(a1.x), accA[1]);
        accA[2] = fmaf(wv.y, bflo(a1.y), accA[2]); accA[3] = fmaf(wv.y, bfhi(a1.y), accA[3]);
        accB[0] = fmaf(wv.y, bflo(a1.z), accB[0]); accB[1] = fmaf(wv.y, bfhi(a1.z), accB[1]);
        accB[2] = fmaf(wv.y, bflo(a1.w), accB[2]); accB[3] = fmaf(wv.y, bfhi(a1.w), accB[3]);
        accA[0] = fmaf(wv.z, bflo(a2.x), accA[0]); accA[1] = fmaf(wv.z, bfhi(a2.x), accA[1]);
        accA[2] = fmaf(wv.z, bflo(a2.y), accA[2]); accA[3] = fmaf(wv.z, bfhi(a2.y), accA[3]);
        accB[0] = fmaf(wv.z, bflo(a2.z), accB[0]); accB[1] = fmaf(wv.z, bfhi(a2.z), accB[1]);
        accB[2] = fmaf(wv.z, bflo(a2.w), accB[2]); accB[3] = fmaf(wv.z, bfhi(a2.w), accB[3]);
        accA[0] = fmaf(wv.w, bflo(a3.x), accA[0]); accA[1] = fmaf(wv.w, bfhi(a3.x), accA[1]);
        accA[2] = fmaf(wv.w, bflo(a3.y), accA[2]); accA[3] = fmaf(wv.w, bfhi(a3.y), accA[3]);
        accB[0] = fmaf(wv.w, bflo(a3.z), accB[0]); accB[1] = fmaf(wv.w, bfhi(a3.z), accB[1]);
        accB[2] = fmaf(wv.w, bflo(a3.w), accB[2]); accB[3] = fmaf(wv.w, bfhi(a3.w), accB[3]);
        a0 = b0; a1 = b1; a2 = b2; a3 = b3;
    }
    us8 r = { f2bf(accA[0]), f2bf(accA[1]), f2bf(accA[2]), f2bf(accA[3]),
              f2bf(accB[0]), f2bf(accB[1]), f2bf(accB[2]), f2bf(accB[3]) };
    *reinterpret_cast<us8*>(msout + (size_t)bq * 256 + h * 32 + j * 8) = r;
}

// ---------------------------------------------------------------------------
extern "C" void kernel_launch(void* const* d_in, const int* in_sizes, int n_in,
                              void* d_out, int out_size, void* d_ws, size_t ws_size,
                              hipStream_t stream) {
    const float* query = (const float*)d_in[0];
    const float* qpos  = (const float*)d_in[1];
    const float* value = (const float*)d_in[2];
    const float* refp  = (const float*)d_in[3];
    const float* W_off  = (const float*)d_in[6];
    const float* b_off  = (const float*)d_in[7];
    const float* W_attn = (const float*)d_in[8];
    const float* b_attn = (const float*)d_in[9];
    const float* W_v    = (const float*)d_in[10];
    const float* b_v    = (const float*)d_in[11];
    const float* W_out  = (const float*)d_in[12];
    const float* b_out  = (const float*)d_in[13];
    const float* ln1_g  = (const float*)d_in[14];
    const float* ln1_b  = (const float*)d_in[15];
    const float* W1     = (const float*)d_in[16];
    const float* b1     = (const float*)d_in[17];
    const float* W2     = (const float*)d_in[18];
    const float* b2     = (const float*)d_in[19];
    const float* ln2_g  = (const float*)d_in[20];
    const float* ln2_b  = (const float*)d_in[21];
    float* out = (float*)d_out;

    // ---- workspace layout ----
    unsigned short* WvT   = (unsigned short*)d_ws;
    unsigned short* WoaT  = WvT   + 65536;    // 384 x 256  (off | attn)
    unsigned short* WoutT = WoaT  + 98304;
    unsigned short* W1T   = WoutT + 65536;    // 1024 x 256
    unsigned short* W2T   = W1T   + 262144;   // 256 x 1024
    float* b_oa = (float*)(W2T + 262144);     // 384 f32
    uint8_t* base = (uint8_t*)(b_oa + 384);
    base = (uint8_t*)(((uintptr_t)base + 255) & ~(uintptr_t)255);

    const size_t A = (size_t)M_ * D_;
    unsigned short* R_v16  = (unsigned short*)base;          // value bf16 -> q1b (LN1 out)
    unsigned short* R_q16  = R_v16 + A;                      // q bf16 -> ms16
    unsigned short* R_vph  = R_q16 + A;                      // vproj bf16 head-major
    float* R_oa  = (float*)(R_vph + A);                      // off|attn (M,384)
    unsigned short* R_h16 = (unsigned short*)(R_oa + (size_t)M_ * 384);  // FFN hidden bf16 (M,1024)

    const dim3 blk(256);
    auto cdiv = [](size_t a, size_t b) { return (unsigned)((a + b - 1) / b); };

    const int n4 = (int)(A / 4);
    prep_kernel<<<cdiv(754048 + 2 * (size_t)n4, 256), blk, 0, stream>>>(
        W_v, W_off, W_attn, W_out, W1, W2, b_off, b_attn, value, query, qpos,
        WvT, WoaT, WoutT, W1T, W2T, b_oa, R_v16, R_q16, n4);

    const unsigned MT = (M_ + 127) / 128;   // 168
    // vproj (head-major bf16, coalesced) + off|attn (f32), one swizzled dispatch
    gemm_pre<<<dim3(5, MT), blk, 0, stream>>>(
        R_v16, R_q16, WvT, WoaT, b_v, b_oa, R_vph, R_oa);
    // deformable attention -> ms16 (overwrites R_q16, dead)
    const unsigned nQC = cdiv(LQ_, 64);   // 168
    msdeform_kernel<<<dim3(nQC * 16), blk, 0, stream>>>(R_vph, R_oa, refp, R_q16);
    // q1b = bf16 LN(query + ms16@WoutT^T + b_out) -> R_v16 (value bf16 dead)
    gemm_ln<0, 0><<<dim3(cdiv(M_, 64)), dim3(512), 0, stream>>>(
        R_q16, WoutT, b_out, query, ln1_g, ln1_b, R_v16, M_, 256);
    // h = relu(q1b @ W1T^T) bf16, swizzled + coalesced epilogue
    gemm_ffn1<<<dim3(8, MT), blk, 0, stream>>>(R_v16, W1T, b1, R_h16, M_, 1024, 256);
    // out = LN(q1b + h@W2T^T + b2), f32 direct
    gemm_ln<1, 1><<<dim3(cdiv(M_, 64)), dim3(512), 0, stream>>>(
        R_h16, W2T, b2, R_v16, ln2_g, ln2_b, out, M_, 1024);
}